// Round 1
// baseline (2023.900 us; speedup 1.0000x reference)
//
#include <hip/hip_runtime.h>

#define NN 50000
#define EE 800000
#define ETOT 850000
#define KIN 61
#define HH 256
#define NH 8
#define CC 32
#define LL 4
#define SCAN_NBLK 49   // ceil(NN/1024)

// ============================ CSR build ============================

__global__ __launch_bounds__(256) void edge_hist(const int* __restrict__ ei,
                                                 int* __restrict__ counts) {
    int e = blockIdx.x * 256 + threadIdx.x;
    if (e >= ETOT) return;
    int d = (e < EE) ? ei[EE + e] : (e - EE);   // row 1 of edge_index = dst; self loops
    atomicAdd(&counts[d], 1);
}

__global__ __launch_bounds__(256) void scan1(const int* __restrict__ counts,
                                             int* __restrict__ tmp,
                                             int* __restrict__ bsums) {
    __shared__ int lds[256];
    int b = blockIdx.x, t = threadIdx.x;
    int base = b * 1024 + t * 4;
    int v0 = 0, v1 = 0, v2 = 0, v3 = 0;
    if (base + 0 < NN) v0 = counts[base + 0];
    if (base + 1 < NN) v1 = counts[base + 1];
    if (base + 2 < NN) v2 = counts[base + 2];
    if (base + 3 < NN) v3 = counts[base + 3];
    int s = v0 + v1 + v2 + v3;
    lds[t] = s;
    __syncthreads();
    for (int off = 1; off < 256; off <<= 1) {
        int x = (t >= off) ? lds[t - off] : 0;
        __syncthreads();
        lds[t] += x;
        __syncthreads();
    }
    int run = lds[t] - s;           // exclusive prefix of this thread
    if (t == 255) bsums[b] = lds[255];
    run += v0; if (base + 0 < NN) tmp[base + 0] = run;
    run += v1; if (base + 1 < NN) tmp[base + 1] = run;
    run += v2; if (base + 2 < NN) tmp[base + 2] = run;
    run += v3; if (base + 3 < NN) tmp[base + 3] = run;
}

__global__ void scan2(int* __restrict__ bsums) {
    if (threadIdx.x == 0) {
        int acc = 0;
        for (int i = 0; i < SCAN_NBLK; ++i) { int t = bsums[i]; bsums[i] = acc; acc += t; }
    }
}

// tmp aliases cursor (elementwise in-place is safe)
__global__ __launch_bounds__(256) void scan3(const int* __restrict__ tmp,
                                             const int* __restrict__ bsums,
                                             const int* __restrict__ counts,
                                             int* __restrict__ rowptr,
                                             int* __restrict__ cursor) {
    int i = blockIdx.x * 256 + threadIdx.x;
    if (i >= NN) return;
    int incl = tmp[i] + bsums[i >> 10];
    rowptr[i + 1] = incl;
    cursor[i] = incl - counts[i];
    if (i == 0) rowptr[0] = 0;
}

__global__ __launch_bounds__(256) void edge_scatter(const int* __restrict__ ei,
                                                    int* __restrict__ cursor,
                                                    int* __restrict__ ssrc) {
    int e = blockIdx.x * 256 + threadIdx.x;
    if (e >= ETOT) return;
    int s, d;
    if (e < EE) { s = ei[e]; d = ei[EE + e]; } else { s = d = e - EE; }
    int pos = atomicAdd(&cursor[d], 1);
    ssrc[pos] = s;
}

// ============================ GEMM [M,K] @ [K,256] ============================
// block 256 = 8 row-groups(rt) x 32 col-threads(jt); thread tile 2 rows x 8 cols.
__global__ __launch_bounds__(256) void gemm256(const float* __restrict__ A,
                                               const float* __restrict__ W,
                                               float* __restrict__ C,
                                               int M, int K) {
    __shared__ float As[16 * 256];
    int Kp = (K + 3) & ~3;
    int row0 = blockIdx.x * 16;
    int tid = threadIdx.x;
    int tot = 16 * Kp;
    for (int idx = tid; idx < tot; idx += 256) {
        int r = idx / Kp;
        int k = idx - r * Kp;
        int gr = row0 + r;
        As[r * Kp + k] = (gr < M && k < K) ? A[gr * K + k] : 0.f;
    }
    __syncthreads();
    int jt = tid & 31;
    int rt = tid >> 5;
    int j0 = jt * 8;
    float acc[2][8];
#pragma unroll
    for (int i = 0; i < 2; ++i)
#pragma unroll
        for (int c = 0; c < 8; ++c) acc[i][c] = 0.f;
    const float* Ar0 = &As[(rt * 2 + 0) * Kp];
    const float* Ar1 = &As[(rt * 2 + 1) * Kp];
    int K4 = K & ~3;
    for (int k = 0; k < K4; k += 4) {
        float4 a0 = *(const float4*)&Ar0[k];
        float4 a1 = *(const float4*)&Ar1[k];
        float a0s[4] = {a0.x, a0.y, a0.z, a0.w};
        float a1s[4] = {a1.x, a1.y, a1.z, a1.w};
#pragma unroll
        for (int kk = 0; kk < 4; ++kk) {
            const float* wr = &W[(k + kk) * 256 + j0];
            float4 w0 = *(const float4*)wr;
            float4 w1 = *(const float4*)(wr + 4);
            acc[0][0] += a0s[kk] * w0.x; acc[0][1] += a0s[kk] * w0.y;
            acc[0][2] += a0s[kk] * w0.z; acc[0][3] += a0s[kk] * w0.w;
            acc[0][4] += a0s[kk] * w1.x; acc[0][5] += a0s[kk] * w1.y;
            acc[0][6] += a0s[kk] * w1.z; acc[0][7] += a0s[kk] * w1.w;
            acc[1][0] += a1s[kk] * w0.x; acc[1][1] += a1s[kk] * w0.y;
            acc[1][2] += a1s[kk] * w0.z; acc[1][3] += a1s[kk] * w0.w;
            acc[1][4] += a1s[kk] * w1.x; acc[1][5] += a1s[kk] * w1.y;
            acc[1][6] += a1s[kk] * w1.z; acc[1][7] += a1s[kk] * w1.w;
        }
    }
    for (int k = K4; k < K; ++k) {
        float a0k = Ar0[k], a1k = Ar1[k];
        const float* wr = &W[k * 256 + j0];
        float4 w0 = *(const float4*)wr;
        float4 w1 = *(const float4*)(wr + 4);
        acc[0][0] += a0k * w0.x; acc[0][1] += a0k * w0.y;
        acc[0][2] += a0k * w0.z; acc[0][3] += a0k * w0.w;
        acc[0][4] += a0k * w1.x; acc[0][5] += a0k * w1.y;
        acc[0][6] += a0k * w1.z; acc[0][7] += a0k * w1.w;
        acc[1][0] += a1k * w0.x; acc[1][1] += a1k * w0.y;
        acc[1][2] += a1k * w0.z; acc[1][3] += a1k * w0.w;
        acc[1][4] += a1k * w1.x; acc[1][5] += a1k * w1.y;
        acc[1][6] += a1k * w1.z; acc[1][7] += a1k * w1.w;
    }
#pragma unroll
    for (int i = 0; i < 2; ++i) {
        int gr = row0 + rt * 2 + i;
        if (gr < M) {
            float4* cp = (float4*)&C[gr * 256 + j0];
            cp[0] = make_float4(acc[i][0], acc[i][1], acc[i][2], acc[i][3]);
            cp[1] = make_float4(acc[i][4], acc[i][5], acc[i][6], acc[i][7]);
        }
    }
}

// ============================ attention scores ============================
__global__ __launch_bounds__(256) void attn_scores(const float* __restrict__ z,
                                                   const float* __restrict__ asrc,
                                                   const float* __restrict__ adst,
                                                   float* __restrict__ esrc,
                                                   float* __restrict__ edst) {
    int t = blockIdx.x * 256 + threadIdx.x;
    if (t >= NN * NH) return;
    int n = t >> 3, hd = t & 7;
    const float* zp = z + n * HH + hd * CC;
    const float* ap = asrc + hd * CC;
    const float* bp = adst + hd * CC;
    float s = 0.f, d = 0.f;
#pragma unroll
    for (int c = 0; c < CC; c += 4) {
        float4 zv = *(const float4*)(zp + c);
        float4 av = *(const float4*)(ap + c);
        float4 bv = *(const float4*)(bp + c);
        s += zv.x * av.x + zv.y * av.y + zv.z * av.z + zv.w * av.w;
        d += zv.x * bv.x + zv.y * bv.y + zv.z * bv.z + zv.w * bv.w;
    }
    esrc[t] = s;
    edst[t] = d;
}

// ============================ softmax stats (online) ============================
__global__ __launch_bounds__(256) void softmax_stats(const int* __restrict__ rowptr,
                                                     const int* __restrict__ ssrc,
                                                     const float* __restrict__ esrc,
                                                     const float* __restrict__ edst,
                                                     float* __restrict__ marr,
                                                     float* __restrict__ darr) {
    int t = blockIdx.x * 256 + threadIdx.x;
    if (t >= NN * NH) return;
    int n = t >> 3, hd = t & 7;
    int beg = rowptr[n], end = rowptr[n + 1];
    float ed = edst[t];
    float m = -1e30f, den = 0.f;
    for (int i = beg; i < end; ++i) {
        int s = ssrc[i];
        float e = esrc[s * NH + hd] + ed;
        e = (e > 0.f) ? e : 0.2f * e;
        float nm = fmaxf(m, e);
        den = den * __expf(m - nm) + __expf(e - nm);
        m = nm;
    }
    marr[t] = m;
    darr[t] = den;
}

// ============================ aggregate (1 wave / node) ============================
__global__ __launch_bounds__(256) void aggregate(const int* __restrict__ rowptr,
                                                 const int* __restrict__ ssrc,
                                                 const float* __restrict__ esrc,
                                                 const float* __restrict__ edst,
                                                 const float* __restrict__ marr,
                                                 const float* __restrict__ darr,
                                                 const float* __restrict__ z,
                                                 float* __restrict__ out) {
    int wid = (blockIdx.x * 256 + threadIdx.x) >> 6;
    int lane = threadIdx.x & 63;
    if (wid >= NN) return;
    int n = wid;
    int hd = lane >> 3;           // head for channels lane*4..lane*4+3
    int t8 = n * NH + hd;
    float ed = edst[t8];
    float m = marr[t8];
    float inv = 1.f / darr[t8];   // >= 1 thanks to self loop
    int c0 = lane * 4;
    float4 acc = make_float4(0.f, 0.f, 0.f, 0.f);
    int beg = rowptr[n], end = rowptr[n + 1];
    for (int i = beg; i < end; ++i) {
        int s = ssrc[i];
        float e = esrc[s * NH + hd] + ed;
        e = (e > 0.f) ? e : 0.2f * e;
        float alpha = __expf(e - m) * inv;
        float4 zv = *(const float4*)&z[s * HH + c0];
        acc.x += alpha * zv.x; acc.y += alpha * zv.y;
        acc.z += alpha * zv.z; acc.w += alpha * zv.w;
    }
    *(float4*)&out[n * HH + c0] = acc;   // conv bias absorbed by BN
}

// ============================ BatchNorm ============================
__global__ __launch_bounds__(256) void col_stats(const float* __restrict__ X,
                                                 float* __restrict__ sums) {
    int c = threadIdx.x;
    int rows_per_block = (NN + gridDim.x - 1) / gridDim.x;
    int r0 = blockIdx.x * rows_per_block;
    int r1 = min(NN, r0 + rows_per_block);
    float s = 0.f, q = 0.f;
    for (int r = r0; r < r1; ++r) {
        float v = X[r * HH + c];
        s += v; q += v * v;
    }
    atomicAdd(&sums[c], s);
    atomicAdd(&sums[HH + c], q);
}

__global__ void bn_finalize(const float* __restrict__ sums, float* __restrict__ mrs) {
    int c = threadIdx.x;
    float mean = sums[c] * (1.f / NN);
    float var = sums[HH + c] * (1.f / NN) - mean * mean;
    var = fmaxf(var, 0.f);
    mrs[c] = mean;
    mrs[HH + c] = rsqrtf(var + 1e-5f);
}

// out = relu((X-mean)*rstd*gamma+beta) [+ res]; res/out may alias elementwise
__global__ __launch_bounds__(256) void bn_relu_add(const float* __restrict__ X,
                                                   const float* __restrict__ mrs,
                                                   const float* __restrict__ gamma,
                                                   const float* __restrict__ beta,
                                                   const float* __restrict__ res,
                                                   float* __restrict__ out) {
    int i = blockIdx.x * 256 + threadIdx.x;
    if (i >= NN * 64) return;
    int c4 = (i & 63) * 4;
    float4 v  = ((const float4*)X)[i];
    float4 mn = *(const float4*)&mrs[c4];
    float4 rs = *(const float4*)&mrs[HH + c4];
    float4 gm = *(const float4*)&gamma[c4];
    float4 bt = *(const float4*)&beta[c4];
    float4 r;
    r.x = fmaxf((v.x - mn.x) * rs.x * gm.x + bt.x, 0.f);
    r.y = fmaxf((v.y - mn.y) * rs.y * gm.y + bt.y, 0.f);
    r.z = fmaxf((v.z - mn.z) * rs.z * gm.z + bt.z, 0.f);
    r.w = fmaxf((v.w - mn.w) * rs.w * gm.w + bt.w, 0.f);
    if (res) {
        float4 rv = ((const float4*)res)[i];
        r.x += rv.x; r.y += rv.y; r.z += rv.z; r.w += rv.w;
    }
    ((float4*)out)[i] = r;
}

// ============================ output projection ============================
__global__ __launch_bounds__(256) void out_proj(const float* __restrict__ h,
                                                const float* __restrict__ mW,
                                                const float* __restrict__ mb,
                                                const float* __restrict__ lW,
                                                const float* __restrict__ lb,
                                                float* __restrict__ out) {
    int wid = (blockIdx.x * 256 + threadIdx.x) >> 6;
    int lane = threadIdx.x & 63;
    if (wid >= NN) return;
    float4 hv = *(const float4*)&h[wid * HH + lane * 4];
    float4 wv = *(const float4*)&mW[lane * 4];
    float4 lv = *(const float4*)&lW[lane * 4];
    float sm = hv.x * wv.x + hv.y * wv.y + hv.z * wv.z + hv.w * wv.w;
    float sl = hv.x * lv.x + hv.y * lv.y + hv.z * lv.z + hv.w * lv.w;
    for (int off = 32; off > 0; off >>= 1) {
        sm += __shfl_down(sm, off);
        sl += __shfl_down(sl, off);
    }
    if (lane == 0) {
        out[wid] = sm + mb[0];
        float l = sl + lb[0];
        out[NN + wid] = fminf(10.f, fmaxf(-10.f, l));
    }
}

// ============================ launch ============================
extern "C" void kernel_launch(void* const* d_in, const int* in_sizes, int n_in,
                              void* d_out, int out_size, void* d_ws, size_t ws_size,
                              hipStream_t stream) {
    const float* x        = (const float*)d_in[0];
    const int*   ei       = (const int*)d_in[1];
    const float* in_W     = (const float*)d_in[2];
    const float* in_gamma = (const float*)d_in[4];
    const float* in_beta  = (const float*)d_in[5];
    const float* Ws       = (const float*)d_in[6];
    const float* att_src  = (const float*)d_in[7];
    const float* att_dst  = (const float*)d_in[8];
    const float* bn_gamma = (const float*)d_in[10];
    const float* bn_beta  = (const float*)d_in[11];
    const float* mean_W   = (const float*)d_in[12];
    const float* mean_b   = (const float*)d_in[13];
    const float* lv_W     = (const float*)d_in[14];
    const float* lv_b     = (const float*)d_in[15];
    float* out = (float*)d_out;

    // workspace layout
    float* h    = (float*)d_ws;
    float* z    = h + (size_t)NN * HH;
    float* agg  = z + (size_t)NN * HH;
    float* esrc = agg + (size_t)NN * HH;
    float* edst = esrc + (size_t)NN * NH;
    float* marr = edst + (size_t)NN * NH;
    float* darr = marr + (size_t)NN * NH;
    float* sums = darr + (size_t)NN * NH;      // 512
    float* mrs  = sums + 512;                  // 512
    int* counts = (int*)(mrs + 512);           // NN
    int* rowptr = counts + NN;                 // NN+1
    int* cursor = rowptr + NN + 1;             // NN (also scan tmp)
    int* ssrc   = cursor + NN;                 // ETOT
    int* bsums  = ssrc + ETOT;                 // 64

    // ---- CSR build ----
    hipMemsetAsync(counts, 0, NN * sizeof(int), stream);
    edge_hist<<<(ETOT + 255) / 256, 256, 0, stream>>>(ei, counts);
    scan1<<<SCAN_NBLK, 256, 0, stream>>>(counts, cursor, bsums);
    scan2<<<1, 64, 0, stream>>>(bsums);
    scan3<<<(NN + 255) / 256, 256, 0, stream>>>(cursor, bsums, counts, rowptr, cursor);
    edge_scatter<<<(ETOT + 255) / 256, 256, 0, stream>>>(ei, cursor, ssrc);

    // ---- input projection + BN + ReLU ----
    gemm256<<<(NN + 15) / 16, 256, 0, stream>>>(x, in_W, agg, NN, KIN);
    hipMemsetAsync(sums, 0, 512 * sizeof(float), stream);
    col_stats<<<256, 256, 0, stream>>>(agg, sums);
    bn_finalize<<<1, 256, 0, stream>>>(sums, mrs);
    bn_relu_add<<<(NN * 64 + 255) / 256, 256, 0, stream>>>(agg, mrs, in_gamma, in_beta, nullptr, h);

    // ---- GAT layers ----
    for (int l = 0; l < LL; ++l) {
        const float* Wl  = Ws + (size_t)l * HH * HH;
        const float* asl = att_src + (size_t)l * NH * CC;
        const float* adl = att_dst + (size_t)l * NH * CC;
        const float* gl  = bn_gamma + (size_t)l * HH;
        const float* bl  = bn_beta + (size_t)l * HH;

        gemm256<<<(NN + 15) / 16, 256, 0, stream>>>(h, Wl, z, NN, HH);
        attn_scores<<<(NN * NH + 255) / 256, 256, 0, stream>>>(z, asl, adl, esrc, edst);
        softmax_stats<<<(NN * NH + 255) / 256, 256, 0, stream>>>(rowptr, ssrc, esrc, edst, marr, darr);
        aggregate<<<(NN * 64 + 255) / 256, 256, 0, stream>>>(rowptr, ssrc, esrc, edst, marr, darr, z, agg);
        hipMemsetAsync(sums, 0, 512 * sizeof(float), stream);
        col_stats<<<256, 256, 0, stream>>>(agg, sums);
        bn_finalize<<<1, 256, 0, stream>>>(sums, mrs);
        bn_relu_add<<<(NN * 64 + 255) / 256, 256, 0, stream>>>(agg, mrs, gl, bl, h, h);
    }

    // ---- output heads ----
    out_proj<<<(NN * 64 + 255) / 256, 256, 0, stream>>>(h, mean_W, mean_b, lv_W, lv_b, out);
}

// Round 2
// 1149.275 us; speedup vs baseline: 1.7610x; 1.7610x over previous
//
#include <hip/hip_runtime.h>

#define NN 50000
#define EE 800000
#define ETOT 850000
#define KIN 61
#define HH 256
#define NH 8
#define CC 32
#define LL 4
#define SCAN_NBLK 49   // ceil(NN/1024)

typedef __attribute__((ext_vector_type(8))) short bf16x8;
typedef __attribute__((ext_vector_type(4))) float f32x4;

__device__ __forceinline__ unsigned short f2b(float f) {
    unsigned u = __builtin_bit_cast(unsigned, f);
    u += 0x7fffu + ((u >> 16) & 1u);   // RNE
    return (unsigned short)(u >> 16);
}
__device__ __forceinline__ float b2f(unsigned short h) {
    unsigned u = ((unsigned)h) << 16;
    return __builtin_bit_cast(float, u);
}

// ============================ CSR build ============================

__global__ __launch_bounds__(256) void edge_hist(const int* __restrict__ ei,
                                                 int* __restrict__ counts) {
    int e = blockIdx.x * 256 + threadIdx.x;
    if (e >= ETOT) return;
    int d = (e < EE) ? ei[EE + e] : (e - EE);
    atomicAdd(&counts[d], 1);
}

__global__ __launch_bounds__(256) void scan1(const int* __restrict__ counts,
                                             int* __restrict__ tmp,
                                             int* __restrict__ bsums) {
    __shared__ int lds[256];
    int b = blockIdx.x, t = threadIdx.x;
    int base = b * 1024 + t * 4;
    int v0 = 0, v1 = 0, v2 = 0, v3 = 0;
    if (base + 0 < NN) v0 = counts[base + 0];
    if (base + 1 < NN) v1 = counts[base + 1];
    if (base + 2 < NN) v2 = counts[base + 2];
    if (base + 3 < NN) v3 = counts[base + 3];
    int s = v0 + v1 + v2 + v3;
    lds[t] = s;
    __syncthreads();
    for (int off = 1; off < 256; off <<= 1) {
        int x = (t >= off) ? lds[t - off] : 0;
        __syncthreads();
        lds[t] += x;
        __syncthreads();
    }
    int run = lds[t] - s;
    if (t == 255) bsums[b] = lds[255];
    run += v0; if (base + 0 < NN) tmp[base + 0] = run;
    run += v1; if (base + 1 < NN) tmp[base + 1] = run;
    run += v2; if (base + 2 < NN) tmp[base + 2] = run;
    run += v3; if (base + 3 < NN) tmp[base + 3] = run;
}

__global__ void scan2(int* __restrict__ bsums) {
    if (threadIdx.x == 0) {
        int acc = 0;
        for (int i = 0; i < SCAN_NBLK; ++i) { int t = bsums[i]; bsums[i] = acc; acc += t; }
    }
}

__global__ __launch_bounds__(256) void scan3(const int* __restrict__ tmp,
                                             const int* __restrict__ bsums,
                                             const int* __restrict__ counts,
                                             int* __restrict__ rowptr,
                                             int* __restrict__ cursor) {
    int i = blockIdx.x * 256 + threadIdx.x;
    if (i >= NN) return;
    int incl = tmp[i] + bsums[i >> 10];
    rowptr[i + 1] = incl;
    cursor[i] = incl - counts[i];
    if (i == 0) rowptr[0] = 0;
}

__global__ __launch_bounds__(256) void edge_scatter(const int* __restrict__ ei,
                                                    int* __restrict__ cursor,
                                                    int* __restrict__ ssrc) {
    int e = blockIdx.x * 256 + threadIdx.x;
    if (e >= ETOT) return;
    int s, d;
    if (e < EE) { s = ei[e]; d = ei[EE + e]; } else { s = d = e - EE; }
    int pos = atomicAdd(&cursor[d], 1);
    ssrc[pos] = s;
}

// ============================ weight / input prep (bf16) ============================

// WT[l][n][k] = bf16(Ws[l][k][n]), k,n in [0,256)
__global__ __launch_bounds__(256) void prep_wt(const float* __restrict__ Ws,
                                               unsigned short* __restrict__ WT) {
    int t = blockIdx.x * 256 + threadIdx.x;
    if (t >= LL * HH * HH) return;
    int l = t >> 16, rem = t & 65535;
    int n = rem >> 8, k = rem & 255;
    WT[t] = f2b(Ws[l * 65536 + k * HH + n]);
}

// inWT[n][k] = bf16(in_W[k][n]) for k<61, else 0. shape [256][64]
__global__ __launch_bounds__(256) void prep_inwt(const float* __restrict__ in_W,
                                                 unsigned short* __restrict__ WT) {
    int t = blockIdx.x * 256 + threadIdx.x;
    if (t >= HH * 64) return;
    int n = t >> 6, k = t & 63;
    WT[t] = (k < KIN) ? f2b(in_W[k * HH + n]) : 0;
}

// xb[n][c] = bf16(x[n][c]) for c<61, else 0. shape [NN][64]
__global__ __launch_bounds__(256) void prep_x(const float* __restrict__ x,
                                              unsigned short* __restrict__ xb) {
    int t = blockIdx.x * 256 + threadIdx.x;
    if (t >= NN * 64) return;
    int n = t >> 6, c = t & 63;
    xb[t] = (c < KIN) ? f2b(x[n * KIN + c]) : 0;
}

// ============================ MFMA GEMM  C = A @ Bt^T ============================
// A: [M][K] bf16, Bt: [256][K] bf16 (Bt[n][k] = W[k][n]), C: [M][256] bf16
// tile 64x64x64, 4 waves (2x2), each wave 32x32 via 2x2 16x16x32 MFMA frags.
__global__ __launch_bounds__(256) void gemm_mfma(const unsigned short* __restrict__ A,
                                                 const unsigned short* __restrict__ Bt,
                                                 unsigned short* __restrict__ C,
                                                 int M, int K) {
    __shared__ unsigned short As[64 * 64];
    __shared__ unsigned short Bs[64 * 64];
    int row0 = blockIdx.x * 64;
    int n0 = blockIdx.y * 64;
    int tid = threadIdx.x;
    int w = tid >> 6, l = tid & 63;
    int wm = w >> 1, wn = w & 1;
    int r15 = l & 15, q = l >> 4;

    f32x4 acc[2][2] = {};

    // staging: thread t stages 2 slots (16B each) of each tile
    int srow = tid >> 2;                 // 0..63
    int ss0 = (tid & 3) * 2;             // 0,2,4,6
    int garow = row0 + srow; if (garow >= M) garow = M - 1;
    int gbrow = n0 + srow;
    int sw = srow & 7;                   // swizzle key
    int base = srow * 64;

    for (int kt = 0; kt < K; kt += 64) {
        if (kt) __syncthreads();
        uint4 av0 = *(const uint4*)&A[(size_t)garow * K + kt + ss0 * 8];
        uint4 av1 = *(const uint4*)&A[(size_t)garow * K + kt + ss0 * 8 + 8];
        uint4 bv0 = *(const uint4*)&Bt[(size_t)gbrow * K + kt + ss0 * 8];
        uint4 bv1 = *(const uint4*)&Bt[(size_t)gbrow * K + kt + ss0 * 8 + 8];
        *(uint4*)&As[base + ((ss0)     ^ sw) * 8] = av0;
        *(uint4*)&As[base + ((ss0 + 1) ^ sw) * 8] = av1;
        *(uint4*)&Bs[base + ((ss0)     ^ sw) * 8] = bv0;
        *(uint4*)&Bs[base + ((ss0 + 1) ^ sw) * 8] = bv1;
        __syncthreads();
#pragma unroll
        for (int kk = 0; kk < 2; ++kk) {
            bf16x8 aF[2], bF[2];
#pragma unroll
            for (int i = 0; i < 2; ++i) {
                int ar = wm * 32 + i * 16 + r15;
                aF[i] = *(bf16x8*)&As[ar * 64 + ((kk * 4 + q) ^ (ar & 7)) * 8];
                int br = wn * 32 + i * 16 + r15;
                bF[i] = *(bf16x8*)&Bs[br * 64 + ((kk * 4 + q) ^ (br & 7)) * 8];
            }
#pragma unroll
            for (int i = 0; i < 2; ++i)
#pragma unroll
                for (int j = 0; j < 2; ++j)
                    acc[i][j] = __builtin_amdgcn_mfma_f32_16x16x32_bf16(aF[i], bF[j], acc[i][j], 0, 0, 0);
        }
    }

    // C/D layout: col = lane&15, row = (lane>>4)*4 + reg
#pragma unroll
    for (int i = 0; i < 2; ++i)
#pragma unroll
        for (int j = 0; j < 2; ++j)
#pragma unroll
            for (int r = 0; r < 4; ++r) {
                int gr = row0 + wm * 32 + i * 16 + q * 4 + r;
                if (gr < M)
                    C[(size_t)gr * HH + n0 + wn * 32 + j * 16 + r15] = f2b(acc[i][j][r]);
            }
}

// ============================ attention scores (z bf16) ============================
__global__ __launch_bounds__(256) void attn_scores(const unsigned short* __restrict__ z,
                                                   const float* __restrict__ asrc,
                                                   const float* __restrict__ adst,
                                                   float* __restrict__ esrc,
                                                   float* __restrict__ edst) {
    int t = blockIdx.x * 256 + threadIdx.x;
    if (t >= NN * NH) return;
    int n = t >> 3, hd = t & 7;
    const unsigned short* zp = z + (size_t)n * HH + hd * CC;
    const float* ap = asrc + hd * CC;
    const float* bp = adst + hd * CC;
    float s = 0.f, d = 0.f;
#pragma unroll
    for (int c = 0; c < CC; c += 4) {
        ushort4 zv = *(const ushort4*)(zp + c);
        float z0 = b2f(zv.x), z1 = b2f(zv.y), z2 = b2f(zv.z), z3 = b2f(zv.w);
        s += z0 * ap[c] + z1 * ap[c + 1] + z2 * ap[c + 2] + z3 * ap[c + 3];
        d += z0 * bp[c] + z1 * bp[c + 1] + z2 * bp[c + 2] + z3 * bp[c + 3];
    }
    esrc[t] = s;
    edst[t] = d;
}

// ============================ softmax stats (online) ============================
__global__ __launch_bounds__(256) void softmax_stats(const int* __restrict__ rowptr,
                                                     const int* __restrict__ ssrc,
                                                     const float* __restrict__ esrc,
                                                     const float* __restrict__ edst,
                                                     float* __restrict__ marr,
                                                     float* __restrict__ darr) {
    int t = blockIdx.x * 256 + threadIdx.x;
    if (t >= NN * NH) return;
    int n = t >> 3, hd = t & 7;
    int beg = rowptr[n], end = rowptr[n + 1];
    float ed = edst[t];
    float m = -1e30f, den = 0.f;
    for (int i = beg; i < end; ++i) {
        int s = ssrc[i];
        float e = esrc[s * NH + hd] + ed;
        e = (e > 0.f) ? e : 0.2f * e;
        float nm = fmaxf(m, e);
        den = den * __expf(m - nm) + __expf(e - nm);
        m = nm;
    }
    marr[t] = m;
    darr[t] = den;
}

// ============================ aggregate (1 wave / node, z bf16) ============================
__global__ __launch_bounds__(256) void aggregate(const int* __restrict__ rowptr,
                                                 const int* __restrict__ ssrc,
                                                 const float* __restrict__ esrc,
                                                 const float* __restrict__ edst,
                                                 const float* __restrict__ marr,
                                                 const float* __restrict__ darr,
                                                 const unsigned short* __restrict__ z,
                                                 float* __restrict__ out) {
    int wid = (blockIdx.x * 256 + threadIdx.x) >> 6;
    int lane = threadIdx.x & 63;
    if (wid >= NN) return;
    int n = wid;
    int hd = lane >> 3;
    int t8 = n * NH + hd;
    float ed = edst[t8];
    float m = marr[t8];
    float inv = 1.f / darr[t8];
    int c0 = lane * 4;
    float a0 = 0.f, a1 = 0.f, a2 = 0.f, a3 = 0.f;
    int beg = rowptr[n], end = rowptr[n + 1];
    for (int i = beg; i < end; ++i) {
        int s = ssrc[i];
        float e = esrc[s * NH + hd] + ed;
        e = (e > 0.f) ? e : 0.2f * e;
        float alpha = __expf(e - m) * inv;
        ushort4 zv = *(const ushort4*)&z[(size_t)s * HH + c0];
        a0 += alpha * b2f(zv.x); a1 += alpha * b2f(zv.y);
        a2 += alpha * b2f(zv.z); a3 += alpha * b2f(zv.w);
    }
    *(float4*)&out[(size_t)n * HH + c0] = make_float4(a0, a1, a2, a3);
}

// ============================ BatchNorm ============================
template<typename TIN>
__global__ __launch_bounds__(256) void col_stats_t(const TIN* __restrict__ X,
                                                   float* __restrict__ sums) {
    int c = threadIdx.x;
    int rows_per_block = (NN + gridDim.x - 1) / gridDim.x;
    int r0 = blockIdx.x * rows_per_block;
    int r1 = min(NN, r0 + rows_per_block);
    float s = 0.f, q = 0.f;
    for (int r = r0; r < r1; ++r) {
        float v;
        if constexpr (sizeof(TIN) == 2) v = b2f((unsigned short)X[(size_t)r * HH + c]);
        else v = X[(size_t)r * HH + c];
        s += v; q += v * v;
    }
    atomicAdd(&sums[c], s);
    atomicAdd(&sums[HH + c], q);
}

__global__ void bn_finalize(const float* __restrict__ sums, float* __restrict__ mrs) {
    int c = threadIdx.x;
    float mean = sums[c] * (1.f / NN);
    float var = sums[HH + c] * (1.f / NN) - mean * mean;
    var = fmaxf(var, 0.f);
    mrs[c] = mean;
    mrs[HH + c] = rsqrtf(var + 1e-5f);
}

// out = relu((X-mean)*rstd*gamma+beta) [+ res]; writes f32 h AND bf16 hb
template<typename TIN>
__global__ __launch_bounds__(256) void bn_relu_add_t(const TIN* __restrict__ X,
                                                     const float* __restrict__ mrs,
                                                     const float* __restrict__ gamma,
                                                     const float* __restrict__ beta,
                                                     const float* __restrict__ res,
                                                     float* __restrict__ outh,
                                                     unsigned short* __restrict__ outb) {
    int i = blockIdx.x * 256 + threadIdx.x;
    if (i >= NN * 64) return;
    int c4 = (i & 63) * 4;
    float v0, v1, v2, v3;
    if constexpr (sizeof(TIN) == 2) {
        ushort4 u = *(const ushort4*)(X + (size_t)i * 4);
        v0 = b2f(u.x); v1 = b2f(u.y); v2 = b2f(u.z); v3 = b2f(u.w);
    } else {
        float4 f = ((const float4*)X)[i];
        v0 = f.x; v1 = f.y; v2 = f.z; v3 = f.w;
    }
    float4 mn = *(const float4*)&mrs[c4];
    float4 rs = *(const float4*)&mrs[HH + c4];
    float4 gm = *(const float4*)&gamma[c4];
    float4 bt = *(const float4*)&beta[c4];
    float r0 = fmaxf((v0 - mn.x) * rs.x * gm.x + bt.x, 0.f);
    float r1 = fmaxf((v1 - mn.y) * rs.y * gm.y + bt.y, 0.f);
    float r2 = fmaxf((v2 - mn.z) * rs.z * gm.z + bt.z, 0.f);
    float r3 = fmaxf((v3 - mn.w) * rs.w * gm.w + bt.w, 0.f);
    if (res) {
        float4 rv = ((const float4*)res)[i];
        r0 += rv.x; r1 += rv.y; r2 += rv.z; r3 += rv.w;
    }
    ((float4*)outh)[i] = make_float4(r0, r1, r2, r3);
    ushort4 ob;
    ob.x = f2b(r0); ob.y = f2b(r1); ob.z = f2b(r2); ob.w = f2b(r3);
    *(ushort4*)(outb + (size_t)i * 4) = ob;
}

// ============================ output projection ============================
__global__ __launch_bounds__(256) void out_proj(const float* __restrict__ h,
                                                const float* __restrict__ mW,
                                                const float* __restrict__ mb,
                                                const float* __restrict__ lW,
                                                const float* __restrict__ lb,
                                                float* __restrict__ out) {
    int wid = (blockIdx.x * 256 + threadIdx.x) >> 6;
    int lane = threadIdx.x & 63;
    if (wid >= NN) return;
    float4 hv = *(const float4*)&h[(size_t)wid * HH + lane * 4];
    float4 wv = *(const float4*)&mW[lane * 4];
    float4 lv = *(const float4*)&lW[lane * 4];
    float sm = hv.x * wv.x + hv.y * wv.y + hv.z * wv.z + hv.w * wv.w;
    float sl = hv.x * lv.x + hv.y * lv.y + hv.z * lv.z + hv.w * lv.w;
    for (int off = 32; off > 0; off >>= 1) {
        sm += __shfl_down(sm, off);
        sl += __shfl_down(sl, off);
    }
    if (lane == 0) {
        out[wid] = sm + mb[0];
        float l = sl + lb[0];
        out[NN + wid] = fminf(10.f, fmaxf(-10.f, l));
    }
}

// ============================ launch ============================
extern "C" void kernel_launch(void* const* d_in, const int* in_sizes, int n_in,
                              void* d_out, int out_size, void* d_ws, size_t ws_size,
                              hipStream_t stream) {
    const float* x        = (const float*)d_in[0];
    const int*   ei       = (const int*)d_in[1];
    const float* in_W     = (const float*)d_in[2];
    const float* in_gamma = (const float*)d_in[4];
    const float* in_beta  = (const float*)d_in[5];
    const float* Ws       = (const float*)d_in[6];
    const float* att_src  = (const float*)d_in[7];
    const float* att_dst  = (const float*)d_in[8];
    const float* bn_gamma = (const float*)d_in[10];
    const float* bn_beta  = (const float*)d_in[11];
    const float* mean_W   = (const float*)d_in[12];
    const float* mean_b   = (const float*)d_in[13];
    const float* lv_W     = (const float*)d_in[14];
    const float* lv_b     = (const float*)d_in[15];
    float* out = (float*)d_out;

    // workspace layout (bytes)
    char* p = (char*)d_ws;
    float* h    = (float*)p;            p += (size_t)NN * HH * 4;
    float* agg  = (float*)p;            p += (size_t)NN * HH * 4;
    unsigned short* z  = (unsigned short*)p;  p += (size_t)NN * HH * 2;
    unsigned short* hb = (unsigned short*)p;  p += (size_t)NN * HH * 2;
    float* esrc = (float*)p;            p += (size_t)NN * NH * 4;
    float* edst = (float*)p;            p += (size_t)NN * NH * 4;
    float* marr = (float*)p;            p += (size_t)NN * NH * 4;
    float* darr = (float*)p;            p += (size_t)NN * NH * 4;
    float* sums = (float*)p;            p += 512 * 4;
    float* mrs  = (float*)p;            p += 512 * 4;
    unsigned short* WT   = (unsigned short*)p; p += (size_t)LL * HH * HH * 2;
    unsigned short* inWT = (unsigned short*)p; p += (size_t)HH * 64 * 2;
    int* counts = (int*)p;              p += (size_t)NN * 4;
    int* rowptr = (int*)p;              p += (size_t)(NN + 1) * 4;
    int* cursor = (int*)p;              p += (size_t)NN * 4;
    int* ssrc   = (int*)p;              p += (size_t)ETOT * 4;
    int* bsums  = (int*)p;              p += 64 * 4;
    unsigned short* xb = hb;  // alias: xb dead before hb first written

    // ---- CSR build ----
    hipMemsetAsync(counts, 0, NN * sizeof(int), stream);
    edge_hist<<<(ETOT + 255) / 256, 256, 0, stream>>>(ei, counts);
    scan1<<<SCAN_NBLK, 256, 0, stream>>>(counts, cursor, bsums);
    scan2<<<1, 64, 0, stream>>>(bsums);
    scan3<<<(NN + 255) / 256, 256, 0, stream>>>(cursor, bsums, counts, rowptr, cursor);
    edge_scatter<<<(ETOT + 255) / 256, 256, 0, stream>>>(ei, cursor, ssrc);

    // ---- bf16 prep ----
    prep_wt<<<(LL * HH * HH + 255) / 256, 256, 0, stream>>>(Ws, WT);
    prep_inwt<<<(HH * 64 + 255) / 256, 256, 0, stream>>>(in_W, inWT);
    prep_x<<<(NN * 64 + 255) / 256, 256, 0, stream>>>(x, xb);

    // ---- input projection + BN + ReLU ----
    {
        dim3 g((NN + 63) / 64, 4);
        gemm_mfma<<<g, 256, 0, stream>>>(xb, inWT, z, NN, 64);
    }
    hipMemsetAsync(sums, 0, 512 * sizeof(float), stream);
    col_stats_t<unsigned short><<<256, 256, 0, stream>>>(z, sums);
    bn_finalize<<<1, 256, 0, stream>>>(sums, mrs);
    bn_relu_add_t<unsigned short><<<(NN * 64 + 255) / 256, 256, 0, stream>>>(
        z, mrs, in_gamma, in_beta, nullptr, h, hb);

    // ---- GAT layers ----
    for (int l = 0; l < LL; ++l) {
        const unsigned short* WTl = WT + (size_t)l * HH * HH;
        const float* asl = att_src + (size_t)l * NH * CC;
        const float* adl = att_dst + (size_t)l * NH * CC;
        const float* gl  = bn_gamma + (size_t)l * HH;
        const float* bl  = bn_beta + (size_t)l * HH;

        dim3 g((NN + 63) / 64, 4);
        gemm_mfma<<<g, 256, 0, stream>>>(hb, WTl, z, NN, HH);
        attn_scores<<<(NN * NH + 255) / 256, 256, 0, stream>>>(z, asl, adl, esrc, edst);
        softmax_stats<<<(NN * NH + 255) / 256, 256, 0, stream>>>(rowptr, ssrc, esrc, edst, marr, darr);
        aggregate<<<(NN * 64 + 255) / 256, 256, 0, stream>>>(rowptr, ssrc, esrc, edst, marr, darr, z, agg);
        hipMemsetAsync(sums, 0, 512 * sizeof(float), stream);
        col_stats_t<float><<<256, 256, 0, stream>>>(agg, sums);
        bn_finalize<<<1, 256, 0, stream>>>(sums, mrs);
        bn_relu_add_t<float><<<(NN * 64 + 255) / 256, 256, 0, stream>>>(
            agg, mrs, gl, bl, h, h, hb);
    }

    // ---- output heads ----
    out_proj<<<(NN * 64 + 255) / 256, 256, 0, stream>>>(h, mean_W, mean_b, lv_W, lv_b, out);
}

// Round 3
// 967.340 us; speedup vs baseline: 2.0922x; 1.1881x over previous
//
#include <hip/hip_runtime.h>

#define NN 50000
#define EE 800000
#define ETOT 850000
#define KIN 61
#define HH 256
#define NH 8
#define CC 32
#define LL 4
#define SCAN_NBLK 49   // ceil(NN/1024)

typedef __attribute__((ext_vector_type(8))) short bf16x8;
typedef __attribute__((ext_vector_type(4))) float f32x4;

__device__ __forceinline__ unsigned short f2b(float f) {
    unsigned u = __builtin_bit_cast(unsigned, f);
    u += 0x7fffu + ((u >> 16) & 1u);   // RNE
    return (unsigned short)(u >> 16);
}
__device__ __forceinline__ float b2f(unsigned short h) {
    unsigned u = ((unsigned)h) << 16;
    return __builtin_bit_cast(float, u);
}

// ============================ CSR build ============================

__global__ __launch_bounds__(256) void edge_hist(const int* __restrict__ ei,
                                                 int* __restrict__ counts) {
    int e = blockIdx.x * 256 + threadIdx.x;
    if (e >= ETOT) return;
    int d = (e < EE) ? ei[EE + e] : (e - EE);
    atomicAdd(&counts[d], 1);
}

__global__ __launch_bounds__(256) void scan1(const int* __restrict__ counts,
                                             int* __restrict__ tmp,
                                             int* __restrict__ bsums) {
    __shared__ int lds[256];
    int b = blockIdx.x, t = threadIdx.x;
    int base = b * 1024 + t * 4;
    int v0 = 0, v1 = 0, v2 = 0, v3 = 0;
    if (base + 0 < NN) v0 = counts[base + 0];
    if (base + 1 < NN) v1 = counts[base + 1];
    if (base + 2 < NN) v2 = counts[base + 2];
    if (base + 3 < NN) v3 = counts[base + 3];
    int s = v0 + v1 + v2 + v3;
    lds[t] = s;
    __syncthreads();
    for (int off = 1; off < 256; off <<= 1) {
        int x = (t >= off) ? lds[t - off] : 0;
        __syncthreads();
        lds[t] += x;
        __syncthreads();
    }
    int run = lds[t] - s;
    if (t == 255) bsums[b] = lds[255];
    run += v0; if (base + 0 < NN) tmp[base + 0] = run;
    run += v1; if (base + 1 < NN) tmp[base + 1] = run;
    run += v2; if (base + 2 < NN) tmp[base + 2] = run;
    run += v3; if (base + 3 < NN) tmp[base + 3] = run;
}

__global__ void scan2(int* __restrict__ bsums) {
    if (threadIdx.x == 0) {
        int acc = 0;
        for (int i = 0; i < SCAN_NBLK; ++i) { int t = bsums[i]; bsums[i] = acc; acc += t; }
    }
}

__global__ __launch_bounds__(256) void scan3(const int* __restrict__ tmp,
                                             const int* __restrict__ bsums,
                                             const int* __restrict__ counts,
                                             int* __restrict__ rowptr,
                                             int* __restrict__ cursor) {
    int i = blockIdx.x * 256 + threadIdx.x;
    if (i >= NN) return;
    int incl = tmp[i] + bsums[i >> 10];
    rowptr[i + 1] = incl;
    cursor[i] = incl - counts[i];
    if (i == 0) rowptr[0] = 0;
}

__global__ __launch_bounds__(256) void edge_scatter(const int* __restrict__ ei,
                                                    int* __restrict__ cursor,
                                                    int* __restrict__ ssrc) {
    int e = blockIdx.x * 256 + threadIdx.x;
    if (e >= ETOT) return;
    int s, d;
    if (e < EE) { s = ei[e]; d = ei[EE + e]; } else { s = d = e - EE; }
    int pos = atomicAdd(&cursor[d], 1);
    ssrc[pos] = s;
}

// sort each row's sources ascending (deterministic 64-lane bitonic).
// Rows longer than 64 (prob ~1e-16 for Poisson(17)) are left unsorted — still correct.
__global__ __launch_bounds__(256) void sort_rows(const int* __restrict__ rowptr,
                                                 int* __restrict__ ssrc) {
    int wid = (blockIdx.x * 256 + threadIdx.x) >> 6;
    int lane = threadIdx.x & 63;
    if (wid >= NN) return;
    int beg = rowptr[wid], end = rowptr[wid + 1];
    int L = end - beg;
    if (L > 64) return;
    int v = (lane < L) ? ssrc[beg + lane] : 0x7fffffff;
#pragma unroll
    for (int k = 2; k <= 64; k <<= 1) {
#pragma unroll
        for (int j = k >> 1; j > 0; j >>= 1) {
            int partner = __shfl_xor(v, j);
            bool up = ((lane & k) == 0);
            bool keepMin = (up == ((lane & j) == 0));
            int mn = min(v, partner), mx = max(v, partner);
            v = keepMin ? mn : mx;
        }
    }
    if (lane < L) ssrc[beg + lane] = v;
}

// ============================ weight / input prep (bf16) ============================

__global__ __launch_bounds__(256) void prep_wt(const float* __restrict__ Ws,
                                               unsigned short* __restrict__ WT) {
    int t = blockIdx.x * 256 + threadIdx.x;
    if (t >= LL * HH * HH) return;
    int l = t >> 16, rem = t & 65535;
    int n = rem >> 8, k = rem & 255;
    WT[t] = f2b(Ws[l * 65536 + k * HH + n]);
}

__global__ __launch_bounds__(256) void prep_inwt(const float* __restrict__ in_W,
                                                 unsigned short* __restrict__ WT) {
    int t = blockIdx.x * 256 + threadIdx.x;
    if (t >= HH * 64) return;
    int n = t >> 6, k = t & 63;
    WT[t] = (k < KIN) ? f2b(in_W[k * HH + n]) : 0;
}

__global__ __launch_bounds__(256) void prep_x(const float* __restrict__ x,
                                              unsigned short* __restrict__ xb) {
    int t = blockIdx.x * 256 + threadIdx.x;
    if (t >= NN * 64) return;
    int n = t >> 6, c = t & 63;
    xb[t] = (c < KIN) ? f2b(x[n * KIN + c]) : 0;
}

// ============================ MFMA GEMM  C = A @ Bt^T ============================
__global__ __launch_bounds__(256) void gemm_mfma(const unsigned short* __restrict__ A,
                                                 const unsigned short* __restrict__ Bt,
                                                 unsigned short* __restrict__ C,
                                                 int M, int K) {
    __shared__ unsigned short As[64 * 64];
    __shared__ unsigned short Bs[64 * 64];
    int row0 = blockIdx.x * 64;
    int n0 = blockIdx.y * 64;
    int tid = threadIdx.x;
    int w = tid >> 6, l = tid & 63;
    int wm = w >> 1, wn = w & 1;
    int r15 = l & 15, q = l >> 4;

    f32x4 acc[2][2] = {};

    int srow = tid >> 2;
    int ss0 = (tid & 3) * 2;
    int garow = row0 + srow; if (garow >= M) garow = M - 1;
    int gbrow = n0 + srow;
    int sw = srow & 7;
    int base = srow * 64;

    for (int kt = 0; kt < K; kt += 64) {
        if (kt) __syncthreads();
        uint4 av0 = *(const uint4*)&A[(size_t)garow * K + kt + ss0 * 8];
        uint4 av1 = *(const uint4*)&A[(size_t)garow * K + kt + ss0 * 8 + 8];
        uint4 bv0 = *(const uint4*)&Bt[(size_t)gbrow * K + kt + ss0 * 8];
        uint4 bv1 = *(const uint4*)&Bt[(size_t)gbrow * K + kt + ss0 * 8 + 8];
        *(uint4*)&As[base + ((ss0)     ^ sw) * 8] = av0;
        *(uint4*)&As[base + ((ss0 + 1) ^ sw) * 8] = av1;
        *(uint4*)&Bs[base + ((ss0)     ^ sw) * 8] = bv0;
        *(uint4*)&Bs[base + ((ss0 + 1) ^ sw) * 8] = bv1;
        __syncthreads();
#pragma unroll
        for (int kk = 0; kk < 2; ++kk) {
            bf16x8 aF[2], bF[2];
#pragma unroll
            for (int i = 0; i < 2; ++i) {
                int ar = wm * 32 + i * 16 + r15;
                aF[i] = *(bf16x8*)&As[ar * 64 + ((kk * 4 + q) ^ (ar & 7)) * 8];
                int br = wn * 32 + i * 16 + r15;
                bF[i] = *(bf16x8*)&Bs[br * 64 + ((kk * 4 + q) ^ (br & 7)) * 8];
            }
#pragma unroll
            for (int i = 0; i < 2; ++i)
#pragma unroll
                for (int j = 0; j < 2; ++j)
                    acc[i][j] = __builtin_amdgcn_mfma_f32_16x16x32_bf16(aF[i], bF[j], acc[i][j], 0, 0, 0);
        }
    }

#pragma unroll
    for (int i = 0; i < 2; ++i)
#pragma unroll
        for (int j = 0; j < 2; ++j)
#pragma unroll
            for (int r = 0; r < 4; ++r) {
                int gr = row0 + wm * 32 + i * 16 + q * 4 + r;
                if (gr < M)
                    C[(size_t)gr * HH + n0 + wn * 32 + j * 16 + r15] = f2b(acc[i][j][r]);
            }
}

// ============================ attention scores (z bf16) ============================
__global__ __launch_bounds__(256) void attn_scores(const unsigned short* __restrict__ z,
                                                   const float* __restrict__ asrc,
                                                   const float* __restrict__ adst,
                                                   float* __restrict__ esrc,
                                                   float* __restrict__ edst) {
    int t = blockIdx.x * 256 + threadIdx.x;
    if (t >= NN * NH) return;
    int n = t >> 3, hd = t & 7;
    const unsigned short* zp = z + (size_t)n * HH + hd * CC;
    const float* ap = asrc + hd * CC;
    const float* bp = adst + hd * CC;
    float s = 0.f, d = 0.f;
#pragma unroll
    for (int c = 0; c < CC; c += 4) {
        ushort4 zv = *(const ushort4*)(zp + c);
        float z0 = b2f(zv.x), z1 = b2f(zv.y), z2 = b2f(zv.z), z3 = b2f(zv.w);
        s += z0 * ap[c] + z1 * ap[c + 1] + z2 * ap[c + 2] + z3 * ap[c + 3];
        d += z0 * bp[c] + z1 * bp[c + 1] + z2 * bp[c + 2] + z3 * bp[c + 3];
    }
    esrc[t] = s;
    edst[t] = d;
}

// ============================ fused aggregate (online softmax, 1 wave/node) ============================
__device__ __forceinline__ void agg_step(float es, float ed, ushort4 zv,
                                         float& m, float& den,
                                         float& a0, float& a1, float& a2, float& a3) {
    float e = es + ed;
    e = (e > 0.f) ? e : 0.2f * e;
    float nm = fmaxf(m, e);
    float sc = __expf(m - nm);
    float p  = __expf(e - nm);
    den = den * sc + p;
    a0 = a0 * sc + p * b2f(zv.x);
    a1 = a1 * sc + p * b2f(zv.y);
    a2 = a2 * sc + p * b2f(zv.z);
    a3 = a3 * sc + p * b2f(zv.w);
    m = nm;
}

__global__ __launch_bounds__(256) void aggregate(const int* __restrict__ rowptr,
                                                 const int* __restrict__ ssrc,
                                                 const float* __restrict__ esrc,
                                                 const float* __restrict__ edst,
                                                 const unsigned short* __restrict__ z,
                                                 unsigned short* __restrict__ outb) {
    int wid = (blockIdx.x * 256 + threadIdx.x) >> 6;
    int lane = threadIdx.x & 63;
    if (wid >= NN) return;
    int hd = lane >> 3;
    float ed = edst[wid * NH + hd];
    int c0 = lane * 4;
    int beg = rowptr[wid], end = rowptr[wid + 1];
    float m = -1e30f, den = 0.f;
    float a0 = 0.f, a1 = 0.f, a2 = 0.f, a3 = 0.f;
    int i = beg;
    for (; i + 2 <= end; i += 2) {
        int s0 = ssrc[i], s1 = ssrc[i + 1];
        float es0 = esrc[s0 * NH + hd];
        float es1 = esrc[s1 * NH + hd];
        ushort4 zv0 = *(const ushort4*)&z[(size_t)s0 * HH + c0];
        ushort4 zv1 = *(const ushort4*)&z[(size_t)s1 * HH + c0];
        agg_step(es0, ed, zv0, m, den, a0, a1, a2, a3);
        agg_step(es1, ed, zv1, m, den, a0, a1, a2, a3);
    }
    if (i < end) {
        int s0 = ssrc[i];
        float es0 = esrc[s0 * NH + hd];
        ushort4 zv0 = *(const ushort4*)&z[(size_t)s0 * HH + c0];
        agg_step(es0, ed, zv0, m, den, a0, a1, a2, a3);
    }
    float inv = 1.f / den;   // row nonempty (self loop)
    ushort4 o;
    o.x = f2b(a0 * inv); o.y = f2b(a1 * inv);
    o.z = f2b(a2 * inv); o.w = f2b(a3 * inv);
    *(ushort4*)&outb[(size_t)wid * HH + c0] = o;
}

// ============================ BatchNorm ============================
__global__ __launch_bounds__(256) void col_stats(const unsigned short* __restrict__ X,
                                                 float* __restrict__ sums) {
    int c = threadIdx.x;
    int rows_per_block = (NN + gridDim.x - 1) / gridDim.x;
    int r0 = blockIdx.x * rows_per_block;
    int r1 = min(NN, r0 + rows_per_block);
    float s = 0.f, q = 0.f;
    for (int r = r0; r < r1; ++r) {
        float v = b2f(X[(size_t)r * HH + c]);
        s += v; q += v * v;
    }
    atomicAdd(&sums[c], s);
    atomicAdd(&sums[HH + c], q);
}

// out = relu((X-mean)*rstd*gamma+beta) [+ res]; BN stats folded in from sums.
__global__ __launch_bounds__(256) void bn_relu_add(const unsigned short* __restrict__ X,
                                                   const float* __restrict__ sums,
                                                   const float* __restrict__ gamma,
                                                   const float* __restrict__ beta,
                                                   const float* __restrict__ res,
                                                   float* __restrict__ outh,
                                                   unsigned short* __restrict__ outb) {
    int i = blockIdx.x * 256 + threadIdx.x;
    if (i >= NN * 64) return;
    int c4 = (i & 63) * 4;
    const float invN = 1.f / NN;
    ushort4 u = *(const ushort4*)(X + (size_t)i * 4);
    float v0 = b2f(u.x), v1 = b2f(u.y), v2 = b2f(u.z), v3 = b2f(u.w);
    float4 s1 = *(const float4*)&sums[c4];
    float4 s2 = *(const float4*)&sums[HH + c4];
    float4 gm = *(const float4*)&gamma[c4];
    float4 bt = *(const float4*)&beta[c4];
    float mn0 = s1.x * invN, mn1 = s1.y * invN, mn2 = s1.z * invN, mn3 = s1.w * invN;
    float rs0 = rsqrtf(fmaxf(s2.x * invN - mn0 * mn0, 0.f) + 1e-5f);
    float rs1 = rsqrtf(fmaxf(s2.y * invN - mn1 * mn1, 0.f) + 1e-5f);
    float rs2 = rsqrtf(fmaxf(s2.z * invN - mn2 * mn2, 0.f) + 1e-5f);
    float rs3 = rsqrtf(fmaxf(s2.w * invN - mn3 * mn3, 0.f) + 1e-5f);
    float r0 = fmaxf((v0 - mn0) * rs0 * gm.x + bt.x, 0.f);
    float r1 = fmaxf((v1 - mn1) * rs1 * gm.y + bt.y, 0.f);
    float r2 = fmaxf((v2 - mn2) * rs2 * gm.z + bt.z, 0.f);
    float r3 = fmaxf((v3 - mn3) * rs3 * gm.w + bt.w, 0.f);
    if (res) {
        float4 rv = ((const float4*)res)[i];
        r0 += rv.x; r1 += rv.y; r2 += rv.z; r3 += rv.w;
    }
    ((float4*)outh)[i] = make_float4(r0, r1, r2, r3);
    ushort4 ob;
    ob.x = f2b(r0); ob.y = f2b(r1); ob.z = f2b(r2); ob.w = f2b(r3);
    *(ushort4*)(outb + (size_t)i * 4) = ob;
}

// ============================ output projection ============================
__global__ __launch_bounds__(256) void out_proj(const float* __restrict__ h,
                                                const float* __restrict__ mW,
                                                const float* __restrict__ mb,
                                                const float* __restrict__ lW,
                                                const float* __restrict__ lb,
                                                float* __restrict__ out) {
    int wid = (blockIdx.x * 256 + threadIdx.x) >> 6;
    int lane = threadIdx.x & 63;
    if (wid >= NN) return;
    float4 hv = *(const float4*)&h[(size_t)wid * HH + lane * 4];
    float4 wv = *(const float4*)&mW[lane * 4];
    float4 lv = *(const float4*)&lW[lane * 4];
    float sm = hv.x * wv.x + hv.y * wv.y + hv.z * wv.z + hv.w * wv.w;
    float sl = hv.x * lv.x + hv.y * lv.y + hv.z * lv.z + hv.w * lv.w;
    for (int off = 32; off > 0; off >>= 1) {
        sm += __shfl_down(sm, off);
        sl += __shfl_down(sl, off);
    }
    if (lane == 0) {
        out[wid] = sm + mb[0];
        float l = sl + lb[0];
        out[NN + wid] = fminf(10.f, fmaxf(-10.f, l));
    }
}

// ============================ launch ============================
extern "C" void kernel_launch(void* const* d_in, const int* in_sizes, int n_in,
                              void* d_out, int out_size, void* d_ws, size_t ws_size,
                              hipStream_t stream) {
    const float* x        = (const float*)d_in[0];
    const int*   ei       = (const int*)d_in[1];
    const float* in_W     = (const float*)d_in[2];
    const float* in_gamma = (const float*)d_in[4];
    const float* in_beta  = (const float*)d_in[5];
    const float* Ws       = (const float*)d_in[6];
    const float* att_src  = (const float*)d_in[7];
    const float* att_dst  = (const float*)d_in[8];
    const float* bn_gamma = (const float*)d_in[10];
    const float* bn_beta  = (const float*)d_in[11];
    const float* mean_W   = (const float*)d_in[12];
    const float* mean_b   = (const float*)d_in[13];
    const float* lv_W     = (const float*)d_in[14];
    const float* lv_b     = (const float*)d_in[15];
    float* out = (float*)d_out;

    // workspace layout (bytes)
    char* p = (char*)d_ws;
    float* h    = (float*)p;                   p += (size_t)NN * HH * 4;
    unsigned short* z    = (unsigned short*)p; p += (size_t)NN * HH * 2;
    unsigned short* hb   = (unsigned short*)p; p += (size_t)NN * HH * 2;
    unsigned short* aggb = (unsigned short*)p; p += (size_t)NN * HH * 2;
    float* esrc = (float*)p;                   p += (size_t)NN * NH * 4;
    float* edst = (float*)p;                   p += (size_t)NN * NH * 4;
    float* sums = (float*)p;                   p += 512 * 4;
    unsigned short* WT   = (unsigned short*)p; p += (size_t)LL * HH * HH * 2;
    unsigned short* inWT = (unsigned short*)p; p += (size_t)HH * 64 * 2;
    int* counts = (int*)p;                     p += (size_t)NN * 4;
    int* rowptr = (int*)p;                     p += (size_t)(NN + 1) * 4;
    int* cursor = (int*)p;                     p += (size_t)NN * 4;
    int* ssrc   = (int*)p;                     p += (size_t)ETOT * 4;
    int* bsums  = (int*)p;                     p += 64 * 4;
    unsigned short* xb = hb;  // alias: xb dead before hb first written

    // ---- CSR build (+ per-row source sort for gather locality) ----
    hipMemsetAsync(counts, 0, NN * sizeof(int), stream);
    edge_hist<<<(ETOT + 255) / 256, 256, 0, stream>>>(ei, counts);
    scan1<<<SCAN_NBLK, 256, 0, stream>>>(counts, cursor, bsums);
    scan2<<<1, 64, 0, stream>>>(bsums);
    scan3<<<(NN + 255) / 256, 256, 0, stream>>>(cursor, bsums, counts, rowptr, cursor);
    edge_scatter<<<(ETOT + 255) / 256, 256, 0, stream>>>(ei, cursor, ssrc);
    sort_rows<<<(NN * 64 + 255) / 256, 256, 0, stream>>>(rowptr, ssrc);

    // ---- bf16 prep ----
    prep_wt<<<(LL * HH * HH + 255) / 256, 256, 0, stream>>>(Ws, WT);
    prep_inwt<<<(HH * 64 + 255) / 256, 256, 0, stream>>>(in_W, inWT);
    prep_x<<<(NN * 64 + 255) / 256, 256, 0, stream>>>(x, xb);

    // ---- input projection + BN + ReLU ----
    {
        dim3 g((NN + 63) / 64, 4);
        gemm_mfma<<<g, 256, 0, stream>>>(xb, inWT, z, NN, 64);
    }
    hipMemsetAsync(sums, 0, 512 * sizeof(float), stream);
    col_stats<<<256, 256, 0, stream>>>(z, sums);
    bn_relu_add<<<(NN * 64 + 255) / 256, 256, 0, stream>>>(z, sums, in_gamma, in_beta,
                                                           nullptr, h, hb);

    // ---- GAT layers ----
    for (int l = 0; l < LL; ++l) {
        const unsigned short* WTl = WT + (size_t)l * HH * HH;
        const float* asl = att_src + (size_t)l * NH * CC;
        const float* adl = att_dst + (size_t)l * NH * CC;
        const float* gl  = bn_gamma + (size_t)l * HH;
        const float* bl  = bn_beta + (size_t)l * HH;

        dim3 g((NN + 63) / 64, 4);
        gemm_mfma<<<g, 256, 0, stream>>>(hb, WTl, z, NN, HH);
        attn_scores<<<(NN * NH + 255) / 256, 256, 0, stream>>>(z, asl, adl, esrc, edst);
        aggregate<<<(NN * 64 + 255) / 256, 256, 0, stream>>>(rowptr, ssrc, esrc, edst, z, aggb);
        hipMemsetAsync(sums, 0, 512 * sizeof(float), stream);
        col_stats<<<256, 256, 0, stream>>>(aggb, sums);
        bn_relu_add<<<(NN * 64 + 255) / 256, 256, 0, stream>>>(aggb, sums, gl, bl, h, h, hb);
    }

    // ---- output heads ----
    out_proj<<<(NN * 64 + 255) / 256, 256, 0, stream>>>(h, mean_W, mean_b, lv_W, lv_b, out);
}

// Round 5
// 925.771 us; speedup vs baseline: 2.1862x; 1.0449x over previous
//
#include <hip/hip_runtime.h>

#define NN 50000
#define EE 800000
#define ETOT 850000
#define KIN 61
#define HH 256
#define NH 8
#define CC 32
#define LL 4
#define SCAN_NBLK 49   // ceil(NN/1024)

typedef __attribute__((ext_vector_type(8))) short bf16x8;
typedef __attribute__((ext_vector_type(4))) float f32x4;

__device__ __forceinline__ unsigned short f2b(float f) {
    unsigned u = __builtin_bit_cast(unsigned, f);
    u += 0x7fffu + ((u >> 16) & 1u);   // RNE
    return (unsigned short)(u >> 16);
}
__device__ __forceinline__ float b2f(unsigned short h) {
    unsigned u = ((unsigned)h) << 16;
    return __builtin_bit_cast(float, u);
}

// ============================ CSR build ============================

__global__ __launch_bounds__(256) void edge_hist(const int* __restrict__ ei,
                                                 int* __restrict__ counts) {
    int e = blockIdx.x * 256 + threadIdx.x;
    if (e >= ETOT) return;
    int d = (e < EE) ? ei[EE + e] : (e - EE);
    atomicAdd(&counts[d], 1);
}

__global__ __launch_bounds__(256) void scan1(const int* __restrict__ counts,
                                             int* __restrict__ tmp,
                                             int* __restrict__ bsums) {
    __shared__ int lds[256];
    int b = blockIdx.x, t = threadIdx.x;
    int base = b * 1024 + t * 4;
    int v0 = 0, v1 = 0, v2 = 0, v3 = 0;
    if (base + 0 < NN) v0 = counts[base + 0];
    if (base + 1 < NN) v1 = counts[base + 1];
    if (base + 2 < NN) v2 = counts[base + 2];
    if (base + 3 < NN) v3 = counts[base + 3];
    int s = v0 + v1 + v2 + v3;
    lds[t] = s;
    __syncthreads();
    for (int off = 1; off < 256; off <<= 1) {
        int x = (t >= off) ? lds[t - off] : 0;
        __syncthreads();
        lds[t] += x;
        __syncthreads();
    }
    int run = lds[t] - s;
    if (t == 255) bsums[b] = lds[255];
    run += v0; if (base + 0 < NN) tmp[base + 0] = run;
    run += v1; if (base + 1 < NN) tmp[base + 1] = run;
    run += v2; if (base + 2 < NN) tmp[base + 2] = run;
    run += v3; if (base + 3 < NN) tmp[base + 3] = run;
}

__global__ void scan2(int* __restrict__ bsums) {
    if (threadIdx.x == 0) {
        int acc = 0;
        for (int i = 0; i < SCAN_NBLK; ++i) { int t = bsums[i]; bsums[i] = acc; acc += t; }
    }
}

__global__ __launch_bounds__(256) void scan3(const int* __restrict__ tmp,
                                             const int* __restrict__ bsums,
                                             const int* __restrict__ counts,
                                             int* __restrict__ rowptr,
                                             int* __restrict__ cursor) {
    int i = blockIdx.x * 256 + threadIdx.x;
    if (i >= NN) return;
    int incl = tmp[i] + bsums[i >> 10];
    rowptr[i + 1] = incl;
    cursor[i] = incl - counts[i];
    if (i == 0) rowptr[0] = 0;
}

__global__ __launch_bounds__(256) void edge_scatter(const int* __restrict__ ei,
                                                    int* __restrict__ cursor,
                                                    int* __restrict__ ssrc) {
    int e = blockIdx.x * 256 + threadIdx.x;
    if (e >= ETOT) return;
    int s, d;
    if (e < EE) { s = ei[e]; d = ei[EE + e]; } else { s = d = e - EE; }
    int pos = atomicAdd(&cursor[d], 1);
    ssrc[pos] = s;
}

// sort each row's sources ascending (deterministic 64-lane bitonic).
// Makes accumulation order canonical (edge_scatter's atomic order varies).
__global__ __launch_bounds__(256) void sort_rows(const int* __restrict__ rowptr,
                                                 int* __restrict__ ssrc) {
    int wid = (blockIdx.x * 256 + threadIdx.x) >> 6;
    int lane = threadIdx.x & 63;
    if (wid >= NN) return;
    int beg = rowptr[wid], end = rowptr[wid + 1];
    int L = end - beg;
    if (L > 64) return;
    int v = (lane < L) ? ssrc[beg + lane] : 0x7fffffff;
#pragma unroll
    for (int k = 2; k <= 64; k <<= 1) {
#pragma unroll
        for (int j = k >> 1; j > 0; j >>= 1) {
            int partner = __shfl_xor(v, j);
            bool up = ((lane & k) == 0);
            bool keepMin = (up == ((lane & j) == 0));
            int mn = min(v, partner), mx = max(v, partner);
            v = keepMin ? mn : mx;
        }
    }
    if (lane < L) ssrc[beg + lane] = v;
}

// ============================ weight / input prep (bf16) ============================

__global__ __launch_bounds__(256) void prep_wt(const float* __restrict__ Ws,
                                               unsigned short* __restrict__ WT) {
    int t = blockIdx.x * 256 + threadIdx.x;
    if (t >= LL * HH * HH) return;
    int l = t >> 16, rem = t & 65535;
    int n = rem >> 8, k = rem & 255;
    WT[t] = f2b(Ws[l * 65536 + k * HH + n]);
}

__global__ __launch_bounds__(256) void prep_inwt(const float* __restrict__ in_W,
                                                 unsigned short* __restrict__ WT) {
    int t = blockIdx.x * 256 + threadIdx.x;
    if (t >= HH * 64) return;
    int n = t >> 6, k = t & 63;
    WT[t] = (k < KIN) ? f2b(in_W[k * HH + n]) : 0;
}

__global__ __launch_bounds__(256) void prep_x(const float* __restrict__ x,
                                              unsigned short* __restrict__ xb) {
    int t = blockIdx.x * 256 + threadIdx.x;
    if (t >= NN * 64) return;
    int n = t >> 6, c = t & 63;
    xb[t] = (c < KIN) ? f2b(x[n * KIN + c]) : 0;
}

// ============================ MFMA GEMM  C = A @ Bt^T ============================
// A: [M][K] bf16, Bt: [256][K] bf16 (Bt[n][k] = W[k][n]), C: [M][256] bf16
// tile 128x128x64, 4 waves (2x2), each wave 64x64 via 4x4 16x16x32 frags.
// NOTE: output spans gridDim.y*128 columns — launch with y = HH/128 = 2 ALWAYS.
__global__ __launch_bounds__(256) void gemm_mfma(const unsigned short* __restrict__ A,
                                                 const unsigned short* __restrict__ Bt,
                                                 unsigned short* __restrict__ C,
                                                 int M, int K) {
    __shared__ unsigned short As[128 * 64];
    __shared__ unsigned short Bs[128 * 64];
    int row0 = blockIdx.x * 128;
    int n0 = blockIdx.y * 128;
    int tid = threadIdx.x;
    int w = tid >> 6, l = tid & 63;
    int wm = w >> 1, wn = w & 1;
    int r15 = l & 15, q = l >> 4;

    f32x4 acc[4][4] = {};

    // staging: thread -> row tid>>1, slots (tid&1)*4 .. +3 (4 x 16B = 64B)
    int srow = tid >> 1;
    int ss0 = (tid & 1) * 4;
    int garow = row0 + srow; if (garow >= M) garow = M - 1;
    int gbrow = n0 + srow;              // always < 256
    int sw = srow & 7;
    int sbase = srow * 64;

    for (int kt = 0; kt < K; kt += 64) {
        if (kt) __syncthreads();
        uint4 av[4], bv[4];
        const unsigned short* ap = &A[(size_t)garow * K + kt + ss0 * 8];
        const unsigned short* bp = &Bt[(size_t)gbrow * K + kt + ss0 * 8];
#pragma unroll
        for (int i = 0; i < 4; ++i) av[i] = *(const uint4*)(ap + i * 8);
#pragma unroll
        for (int i = 0; i < 4; ++i) bv[i] = *(const uint4*)(bp + i * 8);
#pragma unroll
        for (int i = 0; i < 4; ++i) *(uint4*)&As[sbase + ((ss0 + i) ^ sw) * 8] = av[i];
#pragma unroll
        for (int i = 0; i < 4; ++i) *(uint4*)&Bs[sbase + ((ss0 + i) ^ sw) * 8] = bv[i];
        __syncthreads();
#pragma unroll
        for (int kk = 0; kk < 2; ++kk) {
            bf16x8 aF[4], bF[4];
#pragma unroll
            for (int i = 0; i < 4; ++i) {
                int ar = wm * 64 + i * 16 + r15;
                aF[i] = *(bf16x8*)&As[ar * 64 + ((kk * 4 + q) ^ (ar & 7)) * 8];
                int br = wn * 64 + i * 16 + r15;
                bF[i] = *(bf16x8*)&Bs[br * 64 + ((kk * 4 + q) ^ (br & 7)) * 8];
            }
#pragma unroll
            for (int i = 0; i < 4; ++i)
#pragma unroll
                for (int j = 0; j < 4; ++j)
                    acc[i][j] = __builtin_amdgcn_mfma_f32_16x16x32_bf16(aF[i], bF[j], acc[i][j], 0, 0, 0);
        }
    }

    // C/D layout: col = lane&15, row = (lane>>4)*4 + reg
#pragma unroll
    for (int i = 0; i < 4; ++i)
#pragma unroll
        for (int j = 0; j < 4; ++j)
#pragma unroll
            for (int r = 0; r < 4; ++r) {
                int gr = row0 + wm * 64 + i * 16 + q * 4 + r;
                if (gr < M)
                    C[(size_t)gr * HH + n0 + wn * 64 + j * 16 + r15] = f2b(acc[i][j][r]);
            }
}

// ============================ attention scores (z bf16) ============================
__global__ __launch_bounds__(256) void attn_scores(const unsigned short* __restrict__ z,
                                                   const float* __restrict__ asrc,
                                                   const float* __restrict__ adst,
                                                   float* __restrict__ esrc,
                                                   float* __restrict__ edst) {
    int t = blockIdx.x * 256 + threadIdx.x;
    if (t >= NN * NH) return;
    int n = t >> 3, hd = t & 7;
    const unsigned short* zp = z + (size_t)n * HH + hd * CC;
    const float* ap = asrc + hd * CC;
    const float* bp = adst + hd * CC;
    float s = 0.f, d = 0.f;
#pragma unroll
    for (int c = 0; c < CC; c += 4) {
        ushort4 zv = *(const ushort4*)(zp + c);
        float z0 = b2f(zv.x), z1 = b2f(zv.y), z2 = b2f(zv.z), z3 = b2f(zv.w);
        s += z0 * ap[c] + z1 * ap[c + 1] + z2 * ap[c + 2] + z3 * ap[c + 3];
        d += z0 * bp[c] + z1 * bp[c + 1] + z2 * bp[c + 2] + z3 * bp[c + 3];
    }
    esrc[t] = s;
    edst[t] = d;
}

// ============================ fused aggregate (no-max softmax, 1 wave/node) ============================
// Safe without max subtraction: |e| = |leaky(es+ed)| <~ 16 << 88 (fp32 exp range).
__global__ __launch_bounds__(256) void aggregate(const int* __restrict__ rowptr,
                                                 const int* __restrict__ ssrc,
                                                 const float* __restrict__ esrc,
                                                 const float* __restrict__ edst,
                                                 const unsigned short* __restrict__ z,
                                                 unsigned short* __restrict__ outb) {
    int wid = (blockIdx.x * 256 + threadIdx.x) >> 6;
    int lane = threadIdx.x & 63;
    if (wid >= NN) return;
    int hd = lane >> 3;
    float ed = edst[wid * NH + hd];
    int c0 = lane * 4;
    int beg = rowptr[wid], end = rowptr[wid + 1];
    float den0 = 0.f, den1 = 0.f;
    float a00 = 0.f, a01 = 0.f, a02 = 0.f, a03 = 0.f;
    float a10 = 0.f, a11 = 0.f, a12 = 0.f, a13 = 0.f;
    int i = beg;
    for (; i + 2 <= end; i += 2) {
        int s0 = ssrc[i], s1 = ssrc[i + 1];
        float es0 = esrc[s0 * NH + hd];
        float es1 = esrc[s1 * NH + hd];
        ushort4 z0 = *(const ushort4*)&z[(size_t)s0 * HH + c0];
        ushort4 z1 = *(const ushort4*)&z[(size_t)s1 * HH + c0];
        float e0 = es0 + ed; e0 = (e0 > 0.f) ? e0 : 0.2f * e0;
        float e1 = es1 + ed; e1 = (e1 > 0.f) ? e1 : 0.2f * e1;
        float p0 = __expf(e0);
        float p1 = __expf(e1);
        den0 += p0;
        a00 += p0 * b2f(z0.x); a01 += p0 * b2f(z0.y);
        a02 += p0 * b2f(z0.z); a03 += p0 * b2f(z0.w);
        den1 += p1;
        a10 += p1 * b2f(z1.x); a11 += p1 * b2f(z1.y);
        a12 += p1 * b2f(z1.z); a13 += p1 * b2f(z1.w);
    }
    if (i < end) {
        int s0 = ssrc[i];
        float es0 = esrc[s0 * NH + hd];
        ushort4 z0 = *(const ushort4*)&z[(size_t)s0 * HH + c0];
        float e0 = es0 + ed; e0 = (e0 > 0.f) ? e0 : 0.2f * e0;
        float p0 = __expf(e0);
        den0 += p0;
        a00 += p0 * b2f(z0.x); a01 += p0 * b2f(z0.y);
        a02 += p0 * b2f(z0.z); a03 += p0 * b2f(z0.w);
    }
    float inv = 1.f / (den0 + den1);   // row nonempty (self loop)
    ushort4 o;
    o.x = f2b((a00 + a10) * inv); o.y = f2b((a01 + a11) * inv);
    o.z = f2b((a02 + a12) * inv); o.w = f2b((a03 + a13) * inv);
    *(ushort4*)&outb[(size_t)wid * HH + c0] = o;
}

// ============================ BatchNorm ============================
__global__ __launch_bounds__(256) void col_stats(const unsigned short* __restrict__ X,
                                                 float* __restrict__ sums) {
    int c = threadIdx.x;
    int rows_per_block = (NN + gridDim.x - 1) / gridDim.x;
    int r0 = blockIdx.x * rows_per_block;
    int r1 = min(NN, r0 + rows_per_block);
    float s = 0.f, q = 0.f;
    for (int r = r0; r < r1; ++r) {
        float v = b2f(X[(size_t)r * HH + c]);
        s += v; q += v * v;
    }
    atomicAdd(&sums[c], s);
    atomicAdd(&sums[HH + c], q);
}

// out = relu((X-mean)*rstd*gamma+beta) [+ res]; all bf16; res/out may alias (same index).
__global__ __launch_bounds__(256) void bn_relu_add(const unsigned short* __restrict__ X,
                                                   const float* __restrict__ sums,
                                                   const float* __restrict__ gamma,
                                                   const float* __restrict__ beta,
                                                   const unsigned short* __restrict__ res,
                                                   unsigned short* __restrict__ outb) {
    int i = blockIdx.x * 256 + threadIdx.x;
    if (i >= NN * 64) return;
    int c4 = (i & 63) * 4;
    const float invN = 1.f / NN;
    ushort4 u = *(const ushort4*)(X + (size_t)i * 4);
    float v0 = b2f(u.x), v1 = b2f(u.y), v2 = b2f(u.z), v3 = b2f(u.w);
    float4 s1 = *(const float4*)&sums[c4];
    float4 s2 = *(const float4*)&sums[HH + c4];
    float4 gm = *(const float4*)&gamma[c4];
    float4 bt = *(const float4*)&beta[c4];
    float mn0 = s1.x * invN, mn1 = s1.y * invN, mn2 = s1.z * invN, mn3 = s1.w * invN;
    float rs0 = rsqrtf(fmaxf(s2.x * invN - mn0 * mn0, 0.f) + 1e-5f);
    float rs1 = rsqrtf(fmaxf(s2.y * invN - mn1 * mn1, 0.f) + 1e-5f);
    float rs2 = rsqrtf(fmaxf(s2.z * invN - mn2 * mn2, 0.f) + 1e-5f);
    float rs3 = rsqrtf(fmaxf(s2.w * invN - mn3 * mn3, 0.f) + 1e-5f);
    float r0 = fmaxf((v0 - mn0) * rs0 * gm.x + bt.x, 0.f);
    float r1 = fmaxf((v1 - mn1) * rs1 * gm.y + bt.y, 0.f);
    float r2 = fmaxf((v2 - mn2) * rs2 * gm.z + bt.z, 0.f);
    float r3 = fmaxf((v3 - mn3) * rs3 * gm.w + bt.w, 0.f);
    if (res) {
        ushort4 rv = *(const ushort4*)(res + (size_t)i * 4);
        r0 += b2f(rv.x); r1 += b2f(rv.y); r2 += b2f(rv.z); r3 += b2f(rv.w);
    }
    ushort4 ob;
    ob.x = f2b(r0); ob.y = f2b(r1); ob.z = f2b(r2); ob.w = f2b(r3);
    *(ushort4*)(outb + (size_t)i * 4) = ob;
}

// ============================ output projection (h bf16) ============================
__global__ __launch_bounds__(256) void out_proj(const unsigned short* __restrict__ h,
                                                const float* __restrict__ mW,
                                                const float* __restrict__ mb,
                                                const float* __restrict__ lW,
                                                const float* __restrict__ lb,
                                                float* __restrict__ out) {
    int wid = (blockIdx.x * 256 + threadIdx.x) >> 6;
    int lane = threadIdx.x & 63;
    if (wid >= NN) return;
    ushort4 hv = *(const ushort4*)&h[(size_t)wid * HH + lane * 4];
    float h0 = b2f(hv.x), h1 = b2f(hv.y), h2 = b2f(hv.z), h3 = b2f(hv.w);
    float4 wv = *(const float4*)&mW[lane * 4];
    float4 lv = *(const float4*)&lW[lane * 4];
    float sm = h0 * wv.x + h1 * wv.y + h2 * wv.z + h3 * wv.w;
    float sl = h0 * lv.x + h1 * lv.y + h2 * lv.z + h3 * lv.w;
    for (int off = 32; off > 0; off >>= 1) {
        sm += __shfl_down(sm, off);
        sl += __shfl_down(sl, off);
    }
    if (lane == 0) {
        out[wid] = sm + mb[0];
        float l = sl + lb[0];
        out[NN + wid] = fminf(10.f, fmaxf(-10.f, l));
    }
}

// ============================ launch ============================
extern "C" void kernel_launch(void* const* d_in, const int* in_sizes, int n_in,
                              void* d_out, int out_size, void* d_ws, size_t ws_size,
                              hipStream_t stream) {
    const float* x        = (const float*)d_in[0];
    const int*   ei       = (const int*)d_in[1];
    const float* in_W     = (const float*)d_in[2];
    const float* in_gamma = (const float*)d_in[4];
    const float* in_beta  = (const float*)d_in[5];
    const float* Ws       = (const float*)d_in[6];
    const float* att_src  = (const float*)d_in[7];
    const float* att_dst  = (const float*)d_in[8];
    const float* bn_gamma = (const float*)d_in[10];
    const float* bn_beta  = (const float*)d_in[11];
    const float* mean_W   = (const float*)d_in[12];
    const float* mean_b   = (const float*)d_in[13];
    const float* lv_W     = (const float*)d_in[14];
    const float* lv_b     = (const float*)d_in[15];
    float* out = (float*)d_out;

    // workspace layout (bytes)
    char* p = (char*)d_ws;
    unsigned short* z    = (unsigned short*)p; p += (size_t)NN * HH * 2;
    unsigned short* hb   = (unsigned short*)p; p += (size_t)NN * HH * 2;
    unsigned short* aggb = (unsigned short*)p; p += (size_t)NN * HH * 2;
    float* esrc = (float*)p;                   p += (size_t)NN * NH * 4;
    float* edst = (float*)p;                   p += (size_t)NN * NH * 4;
    float* sums = (float*)p;                   p += 512 * 4;
    unsigned short* WT   = (unsigned short*)p; p += (size_t)LL * HH * HH * 2;
    unsigned short* inWT = (unsigned short*)p; p += (size_t)HH * 64 * 2;
    int* counts = (int*)p;                     p += (size_t)NN * 4;
    int* rowptr = (int*)p;                     p += (size_t)(NN + 1) * 4;
    int* cursor = (int*)p;                     p += (size_t)NN * 4;
    int* ssrc   = (int*)p;                     p += (size_t)ETOT * 4;
    int* bsums  = (int*)p;                     p += 64 * 4;
    unsigned short* xb = aggb;  // alias: xb dead before aggb first written

    // ---- CSR build (+ per-row source sort: locality + canonical order) ----
    hipMemsetAsync(counts, 0, NN * sizeof(int), stream);
    edge_hist<<<(ETOT + 255) / 256, 256, 0, stream>>>(ei, counts);
    scan1<<<SCAN_NBLK, 256, 0, stream>>>(counts, cursor, bsums);
    scan2<<<1, 64, 0, stream>>>(bsums);
    scan3<<<(NN + 255) / 256, 256, 0, stream>>>(cursor, bsums, counts, rowptr, cursor);
    edge_scatter<<<(ETOT + 255) / 256, 256, 0, stream>>>(ei, cursor, ssrc);
    sort_rows<<<(NN * 64 + 255) / 256, 256, 0, stream>>>(rowptr, ssrc);

    // ---- bf16 prep ----
    prep_wt<<<(LL * HH * HH + 255) / 256, 256, 0, stream>>>(Ws, WT);
    prep_inwt<<<(HH * 64 + 255) / 256, 256, 0, stream>>>(in_W, inWT);
    prep_x<<<(NN * 64 + 255) / 256, 256, 0, stream>>>(x, xb);

    // ---- input projection + BN + ReLU ----
    {
        dim3 g((NN + 127) / 128, 2);   // FIX: y=2 covers all 256 output cols
        gemm_mfma<<<g, 256, 0, stream>>>(xb, inWT, z, NN, 64);
    }
    hipMemsetAsync(sums, 0, 512 * sizeof(float), stream);
    col_stats<<<256, 256, 0, stream>>>(z, sums);
    bn_relu_add<<<(NN * 64 + 255) / 256, 256, 0, stream>>>(z, sums, in_gamma, in_beta,
                                                           nullptr, hb);

    // ---- GAT layers ----
    for (int l = 0; l < LL; ++l) {
        const unsigned short* WTl = WT + (size_t)l * HH * HH;
        const float* asl = att_src + (size_t)l * NH * CC;
        const float* adl = att_dst + (size_t)l * NH * CC;
        const float* gl  = bn_gamma + (size_t)l * HH;
        const float* bl  = bn_beta + (size_t)l * HH;

        dim3 g((NN + 127) / 128, 2);
        gemm_mfma<<<g, 256, 0, stream>>>(hb, WTl, z, NN, HH);
        attn_scores<<<(NN * NH + 255) / 256, 256, 0, stream>>>(z, asl, adl, esrc, edst);
        aggregate<<<(NN * 64 + 255) / 256, 256, 0, stream>>>(rowptr, ssrc, esrc, edst, z, aggb);
        hipMemsetAsync(sums, 0, 512 * sizeof(float), stream);
        col_stats<<<256, 256, 0, stream>>>(aggb, sums);
        bn_relu_add<<<(NN * 64 + 255) / 256, 256, 0, stream>>>(aggb, sums, gl, bl, hb, hb);
    }

    // ---- output heads ----
    out_proj<<<(NN * 64 + 255) / 256, 256, 0, stream>>>(hb, mean_W, mean_b, lv_W, lv_b, out);
}

// Round 6
// 873.012 us; speedup vs baseline: 2.3183x; 1.0604x over previous
//
#include <hip/hip_runtime.h>

#define NN 50000
#define EE 800000
#define ETOT 850000
#define KIN 61
#define HH 256
#define NH 8
#define CC 32
#define LL 4
#define SCAN_NBLK 49   // ceil(NN/1024)

typedef __attribute__((ext_vector_type(8))) short bf16x8;
typedef __attribute__((ext_vector_type(4))) float f32x4;

__device__ __forceinline__ unsigned short f2b(float f) {
    unsigned u = __builtin_bit_cast(unsigned, f);
    u += 0x7fffu + ((u >> 16) & 1u);   // RNE
    return (unsigned short)(u >> 16);
}
__device__ __forceinline__ float b2f(unsigned short h) {
    unsigned u = ((unsigned)h) << 16;
    return __builtin_bit_cast(float, u);
}

// async global->LDS, 16B per lane; LDS dest is wave-uniform base + lane*16
__device__ __forceinline__ void gload16(const void* g, void* l) {
    __builtin_amdgcn_global_load_lds(
        (const __attribute__((address_space(1))) void*)g,
        (__attribute__((address_space(3))) void*)l, 16, 0, 0);
}

// ============================ CSR build ============================

__global__ __launch_bounds__(256) void edge_hist(const int* __restrict__ ei,
                                                 int* __restrict__ counts) {
    int e = blockIdx.x * 256 + threadIdx.x;
    if (e >= ETOT) return;
    int d = (e < EE) ? ei[EE + e] : (e - EE);
    atomicAdd(&counts[d], 1);
}

__global__ __launch_bounds__(256) void scan1(const int* __restrict__ counts,
                                             int* __restrict__ tmp,
                                             int* __restrict__ bsums) {
    __shared__ int lds[256];
    int b = blockIdx.x, t = threadIdx.x;
    int base = b * 1024 + t * 4;
    int v0 = 0, v1 = 0, v2 = 0, v3 = 0;
    if (base + 0 < NN) v0 = counts[base + 0];
    if (base + 1 < NN) v1 = counts[base + 1];
    if (base + 2 < NN) v2 = counts[base + 2];
    if (base + 3 < NN) v3 = counts[base + 3];
    int s = v0 + v1 + v2 + v3;
    lds[t] = s;
    __syncthreads();
    for (int off = 1; off < 256; off <<= 1) {
        int x = (t >= off) ? lds[t - off] : 0;
        __syncthreads();
        lds[t] += x;
        __syncthreads();
    }
    int run = lds[t] - s;
    if (t == 255) bsums[b] = lds[255];
    run += v0; if (base + 0 < NN) tmp[base + 0] = run;
    run += v1; if (base + 1 < NN) tmp[base + 1] = run;
    run += v2; if (base + 2 < NN) tmp[base + 2] = run;
    run += v3; if (base + 3 < NN) tmp[base + 3] = run;
}

__global__ void scan2(int* __restrict__ bsums) {
    if (threadIdx.x == 0) {
        int acc = 0;
        for (int i = 0; i < SCAN_NBLK; ++i) { int t = bsums[i]; bsums[i] = acc; acc += t; }
    }
}

__global__ __launch_bounds__(256) void scan3(const int* __restrict__ tmp,
                                             const int* __restrict__ bsums,
                                             const int* __restrict__ counts,
                                             int* __restrict__ rowptr,
                                             int* __restrict__ cursor) {
    int i = blockIdx.x * 256 + threadIdx.x;
    if (i >= NN) return;
    int incl = tmp[i] + bsums[i >> 10];
    rowptr[i + 1] = incl;
    cursor[i] = incl - counts[i];
    if (i == 0) rowptr[0] = 0;
}

__global__ __launch_bounds__(256) void edge_scatter(const int* __restrict__ ei,
                                                    int* __restrict__ cursor,
                                                    int* __restrict__ ssrc) {
    int e = blockIdx.x * 256 + threadIdx.x;
    if (e >= ETOT) return;
    int s, d;
    if (e < EE) { s = ei[e]; d = ei[EE + e]; } else { s = d = e - EE; }
    int pos = atomicAdd(&cursor[d], 1);
    ssrc[pos] = s;
}

// sort each row's sources ascending (deterministic 64-lane bitonic).
__global__ __launch_bounds__(256) void sort_rows(const int* __restrict__ rowptr,
                                                 int* __restrict__ ssrc) {
    int wid = (blockIdx.x * 256 + threadIdx.x) >> 6;
    int lane = threadIdx.x & 63;
    if (wid >= NN) return;
    int beg = rowptr[wid], end = rowptr[wid + 1];
    int L = end - beg;
    if (L > 64) return;
    int v = (lane < L) ? ssrc[beg + lane] : 0x7fffffff;
#pragma unroll
    for (int k = 2; k <= 64; k <<= 1) {
#pragma unroll
        for (int j = k >> 1; j > 0; j >>= 1) {
            int partner = __shfl_xor(v, j);
            bool up = ((lane & k) == 0);
            bool keepMin = (up == ((lane & j) == 0));
            int mn = min(v, partner), mx = max(v, partner);
            v = keepMin ? mn : mx;
        }
    }
    if (lane < L) ssrc[beg + lane] = v;
}

// ============================ weight / input prep (bf16) ============================

__global__ __launch_bounds__(256) void prep_wt(const float* __restrict__ Ws,
                                               unsigned short* __restrict__ WT) {
    int t = blockIdx.x * 256 + threadIdx.x;
    if (t >= LL * HH * HH) return;
    int l = t >> 16, rem = t & 65535;
    int n = rem >> 8, k = rem & 255;
    WT[t] = f2b(Ws[l * 65536 + k * HH + n]);
}

__global__ __launch_bounds__(256) void prep_inwt(const float* __restrict__ in_W,
                                                 unsigned short* __restrict__ WT) {
    int t = blockIdx.x * 256 + threadIdx.x;
    if (t >= HH * 64) return;
    int n = t >> 6, k = t & 63;
    WT[t] = (k < KIN) ? f2b(in_W[k * HH + n]) : 0;
}

__global__ __launch_bounds__(256) void prep_x(const float* __restrict__ x,
                                              unsigned short* __restrict__ xb) {
    int t = blockIdx.x * 256 + threadIdx.x;
    if (t >= NN * 64) return;
    int n = t >> 6, c = t & 63;
    xb[t] = (c < KIN) ? f2b(x[n * KIN + c]) : 0;
}

// ============================ MFMA GEMM  C = A @ Bt^T ============================
// A: [M][K] bf16, Bt: [256][K] bf16, C: [M][256] bf16
// tile 128x128x64, 4 waves (2x2), each wave 64x64 via 4x4 16x16x32 frags.
// Staging via global_load_lds width=16: LDS dest LINEAR, XOR swizzle applied to
// the per-lane GLOBAL source slot (slot_g = slot_lds ^ (row&7)) -> LDS contents
// byte-identical to the proven register-staged version; read path unchanged.
// Launch with gridDim.y = HH/128 = 2 ALWAYS.
__global__ __launch_bounds__(256) void gemm_mfma(const unsigned short* __restrict__ A,
                                                 const unsigned short* __restrict__ Bt,
                                                 unsigned short* __restrict__ C,
                                                 int M, int K) {
    __shared__ unsigned short As[128 * 64];
    __shared__ unsigned short Bs[128 * 64];
    int row0 = blockIdx.x * 128;
    int n0 = blockIdx.y * 128;
    int tid = threadIdx.x;
    int w = tid >> 6, l = tid & 63;
    int wm = w >> 1, wn = w & 1;
    int r15 = l & 15, q = l >> 4;

    f32x4 acc[4][4] = {};

    int crow = l >> 3;     // row within 8-row chunk
    int cs   = l & 7;      // 16B slot within row

    for (int kt = 0; kt < K; kt += 64) {
        if (kt) __syncthreads();
#pragma unroll
        for (int c = 0; c < 4; ++c) {
            int r = w * 32 + c * 8 + crow;          // tile row 0..127
            int sg = cs ^ (r & 7);                  // pre-swizzled source slot
            int ga = row0 + r; if (ga >= M) ga = M - 1;
            gload16(&A[(size_t)ga * K + kt + sg * 8], &As[(w * 32 + c * 8) * 64]);
            int gb = n0 + r;                        // < 256 always
            gload16(&Bt[(size_t)gb * K + kt + sg * 8], &Bs[(w * 32 + c * 8) * 64]);
        }
        __syncthreads();
#pragma unroll
        for (int kk = 0; kk < 2; ++kk) {
            bf16x8 aF[4], bF[4];
#pragma unroll
            for (int i = 0; i < 4; ++i) {
                int ar = wm * 64 + i * 16 + r15;
                aF[i] = *(bf16x8*)&As[ar * 64 + ((kk * 4 + q) ^ (ar & 7)) * 8];
                int br = wn * 64 + i * 16 + r15;
                bF[i] = *(bf16x8*)&Bs[br * 64 + ((kk * 4 + q) ^ (br & 7)) * 8];
            }
#pragma unroll
            for (int i = 0; i < 4; ++i)
#pragma unroll
                for (int j = 0; j < 4; ++j)
                    acc[i][j] = __builtin_amdgcn_mfma_f32_16x16x32_bf16(aF[i], bF[j], acc[i][j], 0, 0, 0);
        }
    }

    // C/D layout: col = lane&15, row = (lane>>4)*4 + reg
#pragma unroll
    for (int i = 0; i < 4; ++i)
#pragma unroll
        for (int j = 0; j < 4; ++j)
#pragma unroll
            for (int r = 0; r < 4; ++r) {
                int gr = row0 + wm * 64 + i * 16 + q * 4 + r;
                if (gr < M)
                    C[(size_t)gr * HH + n0 + wn * 64 + j * 16 + r15] = f2b(acc[i][j][r]);
            }
}

// ============================ attention scores (z bf16) ============================
__global__ __launch_bounds__(256) void attn_scores(const unsigned short* __restrict__ z,
                                                   const float* __restrict__ asrc,
                                                   const float* __restrict__ adst,
                                                   float* __restrict__ esrc,
                                                   float* __restrict__ edst) {
    int t = blockIdx.x * 256 + threadIdx.x;
    if (t >= NN * NH) return;
    int n = t >> 3, hd = t & 7;
    const unsigned short* zp = z + (size_t)n * HH + hd * CC;
    const float* ap = asrc + hd * CC;
    const float* bp = adst + hd * CC;
    float s = 0.f, d = 0.f;
#pragma unroll
    for (int c = 0; c < CC; c += 4) {
        ushort4 zv = *(const ushort4*)(zp + c);
        float z0 = b2f(zv.x), z1 = b2f(zv.y), z2 = b2f(zv.z), z3 = b2f(zv.w);
        s += z0 * ap[c] + z1 * ap[c + 1] + z2 * ap[c + 2] + z3 * ap[c + 3];
        d += z0 * bp[c] + z1 * bp[c + 1] + z2 * bp[c + 2] + z3 * bp[c + 3];
    }
    esrc[t] = s;
    edst[t] = d;
}

// ============================ fused aggregate (no-max softmax, 2 waves/node) ============================
// Block = 2 nodes x 2 waves. Each wave takes the parity-half of its node's sorted
// edge list (halves the dependent-gather chain, doubles wave parallelism);
// halves combine via LDS. Deterministic: fixed split, fixed combine order.
// Safe without max subtraction: |e| = |leaky(es+ed)| <~ 16 << 88 (fp32 exp range).
__global__ __launch_bounds__(256) void aggregate(const int* __restrict__ rowptr,
                                                 const int* __restrict__ ssrc,
                                                 const float* __restrict__ esrc,
                                                 const float* __restrict__ edst,
                                                 const unsigned short* __restrict__ z,
                                                 unsigned short* __restrict__ outb) {
    __shared__ float red[2][64 * 5];
    int slot = threadIdx.x >> 7;                  // node within block (0,1)
    int half = (threadIdx.x >> 6) & 1;            // which parity of edges
    int lane = threadIdx.x & 63;
    int n = blockIdx.x * 2 + slot;                // grid = NN/2 exact
    int hd = lane >> 3;
    int c0 = lane * 4;
    float ed = edst[n * NH + hd];
    int beg = rowptr[n], end = rowptr[n + 1];
    float den0 = 0.f, den1 = 0.f;
    float a00 = 0.f, a01 = 0.f, a02 = 0.f, a03 = 0.f;
    float a10 = 0.f, a11 = 0.f, a12 = 0.f, a13 = 0.f;
    int i = beg + half;
    for (; i + 2 < end; i += 4) {
        int s0 = ssrc[i], s1 = ssrc[i + 2];
        float es0 = esrc[s0 * NH + hd];
        float es1 = esrc[s1 * NH + hd];
        ushort4 z0 = *(const ushort4*)&z[(size_t)s0 * HH + c0];
        ushort4 z1 = *(const ushort4*)&z[(size_t)s1 * HH + c0];
        float e0 = es0 + ed; e0 = (e0 > 0.f) ? e0 : 0.2f * e0;
        float e1 = es1 + ed; e1 = (e1 > 0.f) ? e1 : 0.2f * e1;
        float p0 = __expf(e0);
        float p1 = __expf(e1);
        den0 += p0;
        a00 += p0 * b2f(z0.x); a01 += p0 * b2f(z0.y);
        a02 += p0 * b2f(z0.z); a03 += p0 * b2f(z0.w);
        den1 += p1;
        a10 += p1 * b2f(z1.x); a11 += p1 * b2f(z1.y);
        a12 += p1 * b2f(z1.z); a13 += p1 * b2f(z1.w);
    }
    if (i < end) {
        int s0 = ssrc[i];
        float es0 = esrc[s0 * NH + hd];
        ushort4 z0 = *(const ushort4*)&z[(size_t)s0 * HH + c0];
        float e0 = es0 + ed; e0 = (e0 > 0.f) ? e0 : 0.2f * e0;
        float p0 = __expf(e0);
        den0 += p0;
        a00 += p0 * b2f(z0.x); a01 += p0 * b2f(z0.y);
        a02 += p0 * b2f(z0.z); a03 += p0 * b2f(z0.w);
    }
    float a0 = a00 + a10, a1 = a01 + a11, a2 = a02 + a12, a3 = a03 + a13;
    float den = den0 + den1;
    if (half == 1) {
        float* r = &red[slot][lane * 5];
        r[0] = a0; r[1] = a1; r[2] = a2; r[3] = a3; r[4] = den;
    }
    __syncthreads();
    if (half == 0) {
        const float* r = &red[slot][lane * 5];
        a0 += r[0]; a1 += r[1]; a2 += r[2]; a3 += r[3]; den += r[4];
        float inv = 1.f / den;   // row nonempty (self loop)
        ushort4 o;
        o.x = f2b(a0 * inv); o.y = f2b(a1 * inv);
        o.z = f2b(a2 * inv); o.w = f2b(a3 * inv);
        *(ushort4*)&outb[(size_t)n * HH + c0] = o;
    }
}

// ============================ BatchNorm ============================
__global__ __launch_bounds__(256) void col_stats(const unsigned short* __restrict__ X,
                                                 float* __restrict__ sums) {
    int c = threadIdx.x;
    int rows_per_block = (NN + gridDim.x - 1) / gridDim.x;
    int r0 = blockIdx.x * rows_per_block;
    int r1 = min(NN, r0 + rows_per_block);
    float s = 0.f, q = 0.f;
    for (int r = r0; r < r1; ++r) {
        float v = b2f(X[(size_t)r * HH + c]);
        s += v; q += v * v;
    }
    atomicAdd(&sums[c], s);
    atomicAdd(&sums[HH + c], q);
}

// out = relu((X-mean)*rstd*gamma+beta) [+ res]; all bf16; res/out may alias (same index).
__global__ __launch_bounds__(256) void bn_relu_add(const unsigned short* __restrict__ X,
                                                   const float* __restrict__ sums,
                                                   const float* __restrict__ gamma,
                                                   const float* __restrict__ beta,
                                                   const unsigned short* __restrict__ res,
                                                   unsigned short* __restrict__ outb) {
    int i = blockIdx.x * 256 + threadIdx.x;
    if (i >= NN * 64) return;
    int c4 = (i & 63) * 4;
    const float invN = 1.f / NN;
    ushort4 u = *(const ushort4*)(X + (size_t)i * 4);
    float v0 = b2f(u.x), v1 = b2f(u.y), v2 = b2f(u.z), v3 = b2f(u.w);
    float4 s1 = *(const float4*)&sums[c4];
    float4 s2 = *(const float4*)&sums[HH + c4];
    float4 gm = *(const float4*)&gamma[c4];
    float4 bt = *(const float4*)&beta[c4];
    float mn0 = s1.x * invN, mn1 = s1.y * invN, mn2 = s1.z * invN, mn3 = s1.w * invN;
    float rs0 = rsqrtf(fmaxf(s2.x * invN - mn0 * mn0, 0.f) + 1e-5f);
    float rs1 = rsqrtf(fmaxf(s2.y * invN - mn1 * mn1, 0.f) + 1e-5f);
    float rs2 = rsqrtf(fmaxf(s2.z * invN - mn2 * mn2, 0.f) + 1e-5f);
    float rs3 = rsqrtf(fmaxf(s2.w * invN - mn3 * mn3, 0.f) + 1e-5f);
    float r0 = fmaxf((v0 - mn0) * rs0 * gm.x + bt.x, 0.f);
    float r1 = fmaxf((v1 - mn1) * rs1 * gm.y + bt.y, 0.f);
    float r2 = fmaxf((v2 - mn2) * rs2 * gm.z + bt.z, 0.f);
    float r3 = fmaxf((v3 - mn3) * rs3 * gm.w + bt.w, 0.f);
    if (res) {
        ushort4 rv = *(const ushort4*)(res + (size_t)i * 4);
        r0 += b2f(rv.x); r1 += b2f(rv.y); r2 += b2f(rv.z); r3 += b2f(rv.w);
    }
    ushort4 ob;
    ob.x = f2b(r0); ob.y = f2b(r1); ob.z = f2b(r2); ob.w = f2b(r3);
    *(ushort4*)(outb + (size_t)i * 4) = ob;
}

// ============================ output projection (h bf16) ============================
__global__ __launch_bounds__(256) void out_proj(const unsigned short* __restrict__ h,
                                                const float* __restrict__ mW,
                                                const float* __restrict__ mb,
                                                const float* __restrict__ lW,
                                                const float* __restrict__ lb,
                                                float* __restrict__ out) {
    int wid = (blockIdx.x * 256 + threadIdx.x) >> 6;
    int lane = threadIdx.x & 63;
    if (wid >= NN) return;
    ushort4 hv = *(const ushort4*)&h[(size_t)wid * HH + lane * 4];
    float h0 = b2f(hv.x), h1 = b2f(hv.y), h2 = b2f(hv.z), h3 = b2f(hv.w);
    float4 wv = *(const float4*)&mW[lane * 4];
    float4 lv = *(const float4*)&lW[lane * 4];
    float sm = h0 * wv.x + h1 * wv.y + h2 * wv.z + h3 * wv.w;
    float sl = h0 * lv.x + h1 * lv.y + h2 * lv.z + h3 * lv.w;
    for (int off = 32; off > 0; off >>= 1) {
        sm += __shfl_down(sm, off);
        sl += __shfl_down(sl, off);
    }
    if (lane == 0) {
        out[wid] = sm + mb[0];
        float l = sl + lb[0];
        out[NN + wid] = fminf(10.f, fmaxf(-10.f, l));
    }
}

// ============================ launch ============================
extern "C" void kernel_launch(void* const* d_in, const int* in_sizes, int n_in,
                              void* d_out, int out_size, void* d_ws, size_t ws_size,
                              hipStream_t stream) {
    const float* x        = (const float*)d_in[0];
    const int*   ei       = (const int*)d_in[1];
    const float* in_W     = (const float*)d_in[2];
    const float* in_gamma = (const float*)d_in[4];
    const float* in_beta  = (const float*)d_in[5];
    const float* Ws       = (const float*)d_in[6];
    const float* att_src  = (const float*)d_in[7];
    const float* att_dst  = (const float*)d_in[8];
    const float* bn_gamma = (const float*)d_in[10];
    const float* bn_beta  = (const float*)d_in[11];
    const float* mean_W   = (const float*)d_in[12];
    const float* mean_b   = (const float*)d_in[13];
    const float* lv_W     = (const float*)d_in[14];
    const float* lv_b     = (const float*)d_in[15];
    float* out = (float*)d_out;

    // workspace layout (bytes)
    char* p = (char*)d_ws;
    unsigned short* z    = (unsigned short*)p; p += (size_t)NN * HH * 2;
    unsigned short* hb   = (unsigned short*)p; p += (size_t)NN * HH * 2;
    unsigned short* aggb = (unsigned short*)p; p += (size_t)NN * HH * 2;
    float* esrc = (float*)p;                   p += (size_t)NN * NH * 4;
    float* edst = (float*)p;                   p += (size_t)NN * NH * 4;
    float* sums = (float*)p;                   p += 512 * 4;
    unsigned short* WT   = (unsigned short*)p; p += (size_t)LL * HH * HH * 2;
    unsigned short* inWT = (unsigned short*)p; p += (size_t)HH * 64 * 2;
    int* counts = (int*)p;                     p += (size_t)NN * 4;
    int* rowptr = (int*)p;                     p += (size_t)(NN + 1) * 4;
    int* cursor = (int*)p;                     p += (size_t)NN * 4;
    int* ssrc   = (int*)p;                     p += (size_t)ETOT * 4;
    int* bsums  = (int*)p;                     p += 64 * 4;
    unsigned short* xb = aggb;  // alias: xb dead before aggb first written

    // ---- CSR build (+ per-row source sort: locality + canonical order) ----
    hipMemsetAsync(counts, 0, NN * sizeof(int), stream);
    edge_hist<<<(ETOT + 255) / 256, 256, 0, stream>>>(ei, counts);
    scan1<<<SCAN_NBLK, 256, 0, stream>>>(counts, cursor, bsums);
    scan2<<<1, 64, 0, stream>>>(bsums);
    scan3<<<(NN + 255) / 256, 256, 0, stream>>>(cursor, bsums, counts, rowptr, cursor);
    edge_scatter<<<(ETOT + 255) / 256, 256, 0, stream>>>(ei, cursor, ssrc);
    sort_rows<<<(NN * 64 + 255) / 256, 256, 0, stream>>>(rowptr, ssrc);

    // ---- bf16 prep ----
    prep_wt<<<(LL * HH * HH + 255) / 256, 256, 0, stream>>>(Ws, WT);
    prep_inwt<<<(HH * 64 + 255) / 256, 256, 0, stream>>>(in_W, inWT);
    prep_x<<<(NN * 64 + 255) / 256, 256, 0, stream>>>(x, xb);

    // ---- input projection + BN + ReLU ----
    {
        dim3 g((NN + 127) / 128, 2);   // y=2 covers all 256 output cols
        gemm_mfma<<<g, 256, 0, stream>>>(xb, inWT, z, NN, 64);
    }
    hipMemsetAsync(sums, 0, 512 * sizeof(float), stream);
    col_stats<<<1024, 256, 0, stream>>>(z, sums);
    bn_relu_add<<<(NN * 64 + 255) / 256, 256, 0, stream>>>(z, sums, in_gamma, in_beta,
                                                           nullptr, hb);

    // ---- GAT layers ----
    for (int l = 0; l < LL; ++l) {
        const unsigned short* WTl = WT + (size_t)l * HH * HH;
        const float* asl = att_src + (size_t)l * NH * CC;
        const float* adl = att_dst + (size_t)l * NH * CC;
        const float* gl  = bn_gamma + (size_t)l * HH;
        const float* bl  = bn_beta + (size_t)l * HH;

        dim3 g((NN + 127) / 128, 2);
        gemm_mfma<<<g, 256, 0, stream>>>(hb, WTl, z, NN, HH);
        attn_scores<<<(NN * NH + 255) / 256, 256, 0, stream>>>(z, asl, adl, esrc, edst);
        aggregate<<<NN / 2, 256, 0, stream>>>(rowptr, ssrc, esrc, edst, z, aggb);
        hipMemsetAsync(sums, 0, 512 * sizeof(float), stream);
        col_stats<<<1024, 256, 0, stream>>>(aggb, sums);
        bn_relu_add<<<(NN * 64 + 255) / 256, 256, 0, stream>>>(aggb, sums, gl, bl, hb, hb);
    }

    // ---- output heads ----
    out_proj<<<(NN * 64 + 255) / 256, 256, 0, stream>>>(hb, mean_W, mean_b, lv_W, lv_b, out);
}